// Round 12
// baseline (3063.811 us; speedup 1.0000x reference)
//
#include <hip/hip_runtime.h>
#include <hip/hip_bf16.h>

#define BB_ 16
#define T_ 2048
#define DIN_ 64
#define D_ 512
#define DI_ 1024
#define N_ 16
#define DC_ 4
#define R_ 32
#define L_ 3
#define DOUT_ 128
#define CL_ 128              // scan chunk length
#define NCH_ (T_ / CL_)      // 16 chunks

typedef __attribute__((ext_vector_type(8))) _Float16 f16x8;
typedef __attribute__((ext_vector_type(4))) float f32x4;

__device__ __forceinline__ float silu_f(float x) { return x / (1.f + __expf(-x)); }

__device__ __forceinline__ unsigned short f2h(float f) {
    union { _Float16 h; unsigned short u; } c;
    c.h = (_Float16)f;   // RNE
    return c.u;
}

// decode scale from amax bits: s = 2^(11 - e), so s*amax lands in [2^11, 2^12)
__device__ __forceinline__ float decode_scale(unsigned int bits) {
    if (bits == 0u) return 1.f;
    const int E = (int)(bits >> 23) & 0xFF;
    return __uint_as_float((unsigned)(265 - E) << 23);
}

__device__ __forceinline__ uint4 pack8(float4 lo, float4 hi, float s) {
    union { uint4 u; unsigned short h[8]; } r;
    r.h[0] = f2h(lo.x * s); r.h[1] = f2h(lo.y * s);
    r.h[2] = f2h(lo.z * s); r.h[3] = f2h(lo.w * s);
    r.h[4] = f2h(hi.x * s); r.h[5] = f2h(hi.y * s);
    r.h[6] = f2h(hi.z * s); r.h[7] = f2h(hi.w * s);
    return r.u;
}

// regions: 0-2 Win[l] (262144 f4), 3-5 Wout[l] (131072), 6 Wo (16384),
// 7-9 Wx[l] (16384), 10-12 Wdt[l] (8192). slot == region.
__device__ __forceinline__ const float* wregion(
    int r, const float* Win, const float* Wout, const float* Wx,
    const float* Wdt, const float* Wo, size_t* n4)
{
    if (r < 3)       { *n4 = 262144; return Win  + (size_t)r * 1048576; }
    else if (r < 6)  { *n4 = 131072; return Wout + (size_t)(r - 3) * 524288; }
    else if (r == 6) { *n4 = 16384;  return Wo; }
    else if (r < 10) { *n4 = 16384;  return Wx  + (size_t)(r - 7) * 65536; }
    else             { *n4 = 8192;   return Wdt + (size_t)(r - 10) * 32768; }
}

__global__ __launch_bounds__(256) void amax_all(
    const float* __restrict__ Win, const float* __restrict__ Wout,
    const float* __restrict__ Wx, const float* __restrict__ Wdt,
    const float* __restrict__ Wo, unsigned int* __restrict__ scales)
{
    size_t n4;
    const float* p = wregion(blockIdx.z, Win, Wout, Wx, Wdt, Wo, &n4);
    float m = 0.f;
    for (size_t i = (size_t)blockIdx.x * 256 + threadIdx.x; i < n4;
         i += (size_t)gridDim.x * 256) {
        const float4 v = ((const float4*)p)[i];
        m = fmaxf(m, fmaxf(fmaxf(fabsf(v.x), fabsf(v.y)),
                           fmaxf(fabsf(v.z), fabsf(v.w))));
    }
#pragma unroll
    for (int off = 32; off; off >>= 1) m = fmaxf(m, __shfl_down(m, off));
    __shared__ float sm[4];
    if ((threadIdx.x & 63) == 0) sm[threadIdx.x >> 6] = m;
    __syncthreads();
    if (threadIdx.x == 0) {
        const float b = fmaxf(fmaxf(sm[0], sm[1]), fmaxf(sm[2], sm[3]));
        atomicMax(scales + blockIdx.z, __float_as_uint(b));
    }
}

__global__ __launch_bounds__(256) void cast_all(
    const float* __restrict__ Win, const float* __restrict__ Wout,
    const float* __restrict__ Wx, const float* __restrict__ Wdt,
    const float* __restrict__ Wo,
    unsigned short* __restrict__ WinH, unsigned short* __restrict__ WoutH,
    unsigned short* __restrict__ WxH, unsigned short* __restrict__ WdtH,
    unsigned short* __restrict__ WoH,
    const unsigned int* __restrict__ scales)
{
    const int r = blockIdx.z;
    size_t n4;
    const float* p = wregion(r, Win, Wout, Wx, Wdt, Wo, &n4);
    unsigned short* o;
    if (r < 3)       o = WinH  + (size_t)r * 1048576;
    else if (r < 6)  o = WoutH + (size_t)(r - 3) * 524288;
    else if (r == 6) o = WoH;
    else if (r < 10) o = WxH   + (size_t)(r - 7) * 65536;
    else             o = WdtH  + (size_t)(r - 10) * 32768;
    const float s = decode_scale(scales[r]);
    for (size_t i = (size_t)blockIdx.x * 256 + threadIdx.x; i < n4;
         i += (size_t)gridDim.x * 256) {
        const float4 v = ((const float4*)p)[i];
        ((ushort4*)o)[i] = make_ushort4(f2h(v.x * s), f2h(v.y * s),
                                        f2h(v.z * s), f2h(v.w * s));
    }
}

// ------- scaled MFMA GEMM, A fp32 (cast during LDS staging), B f16 --------
// 128x128 tile, BK=32, 4 waves (2x2), per-wave 64x64 = 4x4 frags of 16x16x32.
// Pipelined: next-step global loads issued before MFMA cluster.
// ACT: 0 = none, 3 = +bias tanh. Output fp32 (+ optional amax).
// NOTE: C must NOT alias A (blocks read A rows outside their C tile).
template<int ACT>
__global__ __launch_bounds__(256) void gemm_f32a_t128(
    const float* __restrict__ A, int lda,
    const unsigned short* __restrict__ B, int ldb,
    const float* __restrict__ bias,
    float* __restrict__ C, int ldc, int K,
    const unsigned int* __restrict__ sa, const unsigned int* __restrict__ sb,
    unsigned int* __restrict__ oamax)
{
    __shared__ __align__(16) unsigned short As[128 * 32];
    __shared__ __align__(16) unsigned short Bs[128 * 32];
    const int tid  = threadIdx.x;
    const int lane = tid & 63;
    const int w    = tid >> 6;
    const int wr   = (w >> 1) << 6;
    const int wc   = (w & 1) << 6;
    const int l15  = lane & 15, l4 = lane >> 4;
    const int row0 = blockIdx.y << 7, col0 = blockIdx.x << 7;
    const int tq   = tid >> 2;
    const int tr   = (tid & 3) << 3;

    const float sA  = decode_scale(*sa);
    const float inv = (1.f / sA) * (1.f / decode_scale(*sb));

    const float* Ar0 = A + (size_t)(row0 + tq) * lda + tr;
    const float* Ar1 = A + (size_t)(row0 + 64 + tq) * lda + tr;
    const unsigned short* Br0 = B + (size_t)(col0 + tq) * ldb + tr;
    const unsigned short* Br1 = B + (size_t)(col0 + 64 + tq) * ldb + tr;

    f32x4 acc[4][4];
#pragma unroll
    for (int m = 0; m < 4; ++m)
#pragma unroll
        for (int n = 0; n < 4; ++n) acc[m][n] = (f32x4){0.f, 0.f, 0.f, 0.f};

    float4 a0lo = *(const float4*)(Ar0), a0hi = *(const float4*)(Ar0 + 4);
    float4 a1lo = *(const float4*)(Ar1), a1hi = *(const float4*)(Ar1 + 4);
    uint4  bv0  = *(const uint4*)(Br0);
    uint4  bv1  = *(const uint4*)(Br1);

    for (int k0 = 0; k0 < K; k0 += 32) {
        __syncthreads();
        *(uint4*)&As[tq * 32 + tr]        = pack8(a0lo, a0hi, sA);
        *(uint4*)&As[(64 + tq) * 32 + tr] = pack8(a1lo, a1hi, sA);
        *(uint4*)&Bs[tq * 32 + tr]        = bv0;
        *(uint4*)&Bs[(64 + tq) * 32 + tr] = bv1;
        __syncthreads();

        if (k0 + 32 < K) {
            a0lo = *(const float4*)(Ar0 + k0 + 32);
            a0hi = *(const float4*)(Ar0 + k0 + 36);
            a1lo = *(const float4*)(Ar1 + k0 + 32);
            a1hi = *(const float4*)(Ar1 + k0 + 36);
            bv0  = *(const uint4*)(Br0 + k0 + 32);
            bv1  = *(const uint4*)(Br1 + k0 + 32);
        }

        f16x8 af[4], bfr[4];
#pragma unroll
        for (int m = 0; m < 4; ++m)
            af[m] = *(const f16x8*)&As[(wr + m * 16 + l15) * 32 + l4 * 8];
#pragma unroll
        for (int n = 0; n < 4; ++n)
            bfr[n] = *(const f16x8*)&Bs[(wc + n * 16 + l15) * 32 + l4 * 8];
#pragma unroll
        for (int m = 0; m < 4; ++m)
#pragma unroll
            for (int n = 0; n < 4; ++n)
                acc[m][n] = __builtin_amdgcn_mfma_f32_16x16x32_f16(
                    af[m], bfr[n], acc[m][n], 0, 0, 0);
    }

    float am = 0.f;
#pragma unroll
    for (int n = 0; n < 4; ++n) {
        const int col = col0 + wc + n * 16 + l15;
        float bc = 0.f;
        if (ACT == 3) bc = bias[col];
#pragma unroll
        for (int m = 0; m < 4; ++m) {
            const int rowb = row0 + wr + m * 16 + (l4 << 2);
#pragma unroll
            for (int r = 0; r < 4; ++r) {
                float v = acc[m][n][r] * inv;
                if (ACT == 3) v = tanhf(v + bc);
                C[(size_t)(rowb + r) * ldc + col] = v;
                am = fmaxf(am, fabsf(v));
            }
        }
    }
    if (oamax) {
#pragma unroll
        for (int off = 32; off; off >>= 1) am = fmaxf(am, __shfl_down(am, off));
        if (lane == 0) atomicMax(oamax, __float_as_uint(am));
    }
}

// ---- dbc GEMM: A fp32 u (staged cast), B f16 Wx. 128x64 tile, pipelined.
// Also emits amax over output cols 0..31 (= dt) for the delta GEMM.
__global__ __launch_bounds__(256) void gemm_f16u_t64n(
    const float* __restrict__ A, int lda,
    const unsigned short* __restrict__ B, int ldb,
    float* __restrict__ C, int ldc, int K,
    const unsigned int* __restrict__ sa, const unsigned int* __restrict__ sb,
    unsigned int* __restrict__ dtmax)
{
    __shared__ __align__(16) unsigned short As[128 * 32];
    __shared__ __align__(16) unsigned short Bs[64 * 32];
    const int tid  = threadIdx.x;
    const int lane = tid & 63;
    const int w    = tid >> 6;
    const int l15  = lane & 15, l4 = lane >> 4;
    const int row0 = blockIdx.y << 7;
    const int tq   = tid >> 2;
    const int tr   = (tid & 3) << 3;

    const float sA  = decode_scale(*sa);
    const float inv = (1.f / sA) * (1.f / decode_scale(*sb));

    const float* Ar0 = A + (size_t)(row0 + tq) * lda + tr;
    const float* Ar1 = A + (size_t)(row0 + 64 + tq) * lda + tr;
    const unsigned short* Br = B + (size_t)tq * ldb + tr;   // 64 rows

    f32x4 acc[2][4];
#pragma unroll
    for (int m = 0; m < 2; ++m)
#pragma unroll
        for (int n = 0; n < 4; ++n) acc[m][n] = (f32x4){0.f, 0.f, 0.f, 0.f};

    float4 a0lo = *(const float4*)(Ar0), a0hi = *(const float4*)(Ar0 + 4);
    float4 a1lo = *(const float4*)(Ar1), a1hi = *(const float4*)(Ar1 + 4);
    uint4  bv   = *(const uint4*)(Br);

    for (int k0 = 0; k0 < K; k0 += 32) {
        __syncthreads();
        *(uint4*)&As[tq * 32 + tr]        = pack8(a0lo, a0hi, sA);
        *(uint4*)&As[(64 + tq) * 32 + tr] = pack8(a1lo, a1hi, sA);
        *(uint4*)&Bs[tq * 32 + tr]        = bv;
        __syncthreads();

        if (k0 + 32 < K) {
            a0lo = *(const float4*)(Ar0 + k0 + 32);
            a0hi = *(const float4*)(Ar0 + k0 + 36);
            a1lo = *(const float4*)(Ar1 + k0 + 32);
            a1hi = *(const float4*)(Ar1 + k0 + 36);
            bv   = *(const uint4*)(Br  + k0 + 32);
        }

        f16x8 af[2], bfr[4];
#pragma unroll
        for (int m = 0; m < 2; ++m)
            af[m] = *(const f16x8*)&As[(w * 32 + m * 16 + l15) * 32 + l4 * 8];
#pragma unroll
        for (int n = 0; n < 4; ++n)
            bfr[n] = *(const f16x8*)&Bs[(n * 16 + l15) * 32 + l4 * 8];
#pragma unroll
        for (int m = 0; m < 2; ++m)
#pragma unroll
            for (int n = 0; n < 4; ++n)
                acc[m][n] = __builtin_amdgcn_mfma_f32_16x16x32_f16(
                    af[m], bfr[n], acc[m][n], 0, 0, 0);
    }

    float am = 0.f;
#pragma unroll
    for (int n = 0; n < 4; ++n) {
        const int col = n * 16 + l15;
#pragma unroll
        for (int m = 0; m < 2; ++m) {
            const int rowb = row0 + w * 32 + m * 16 + (l4 << 2);
#pragma unroll
            for (int r = 0; r < 4; ++r) {
                const float v = acc[m][n][r] * inv;
                C[(size_t)(rowb + r) * ldc + col] = v;
                if (n < 2) am = fmaxf(am, fabsf(v));   // dt cols 0..31
            }
        }
    }
#pragma unroll
    for (int off = 32; off; off >>= 1) am = fmaxf(am, __shfl_down(am, off));
    if (lane == 0) atomicMax(dtmax, __float_as_uint(am));
}

// ---- delta GEMM (K=32, single MFMA step): delta = softplus(dt@Wdt.T + bdt)
// A = dbc fp32 (lda 64, cols 0..31, staged cast), B = Wdt f16 (ldb 32).
// Output fp32 strided (ldc 2048) into the xin slot of xz.
__global__ __launch_bounds__(256) void gemm_delta(
    const float* __restrict__ A,
    const unsigned short* __restrict__ B,
    const float* __restrict__ bias,
    float* __restrict__ C, int ldc,
    const unsigned int* __restrict__ sa, const unsigned int* __restrict__ sb)
{
    __shared__ __align__(16) unsigned short As[128 * 32];
    __shared__ __align__(16) unsigned short Bs[128 * 32];
    const int tid  = threadIdx.x;
    const int lane = tid & 63;
    const int w    = tid >> 6;
    const int wr   = (w >> 1) << 6;
    const int wc   = (w & 1) << 6;
    const int l15  = lane & 15, l4 = lane >> 4;
    const int row0 = blockIdx.y << 7, col0 = blockIdx.x << 7;
    const int tq   = tid >> 2;
    const int tr   = (tid & 3) << 3;

    const float sA  = decode_scale(*sa);
    const float inv = (1.f / sA) * (1.f / decode_scale(*sb));

    const float* Ar0 = A + (size_t)(row0 + tq) * 64 + tr;
    const float* Ar1 = A + (size_t)(row0 + 64 + tq) * 64 + tr;
    const float4 a0lo = *(const float4*)(Ar0), a0hi = *(const float4*)(Ar0 + 4);
    const float4 a1lo = *(const float4*)(Ar1), a1hi = *(const float4*)(Ar1 + 4);
    const uint4 bv0 = *(const uint4*)(B + (size_t)(col0 + tq) * 32 + tr);
    const uint4 bv1 = *(const uint4*)(B + (size_t)(col0 + 64 + tq) * 32 + tr);

    *(uint4*)&As[tq * 32 + tr]        = pack8(a0lo, a0hi, sA);
    *(uint4*)&As[(64 + tq) * 32 + tr] = pack8(a1lo, a1hi, sA);
    *(uint4*)&Bs[tq * 32 + tr]        = bv0;
    *(uint4*)&Bs[(64 + tq) * 32 + tr] = bv1;
    __syncthreads();

    f32x4 acc[4][4];
#pragma unroll
    for (int m = 0; m < 4; ++m)
#pragma unroll
        for (int n = 0; n < 4; ++n) acc[m][n] = (f32x4){0.f, 0.f, 0.f, 0.f};

    f16x8 af[4], bfr[4];
#pragma unroll
    for (int m = 0; m < 4; ++m)
        af[m] = *(const f16x8*)&As[(wr + m * 16 + l15) * 32 + l4 * 8];
#pragma unroll
    for (int n = 0; n < 4; ++n)
        bfr[n] = *(const f16x8*)&Bs[(wc + n * 16 + l15) * 32 + l4 * 8];
#pragma unroll
    for (int m = 0; m < 4; ++m)
#pragma unroll
        for (int n = 0; n < 4; ++n)
            acc[m][n] = __builtin_amdgcn_mfma_f32_16x16x32_f16(
                af[m], bfr[n], acc[m][n], 0, 0, 0);

#pragma unroll
    for (int n = 0; n < 4; ++n) {
        const int col = col0 + wc + n * 16 + l15;
        const float bc = bias[col];
#pragma unroll
        for (int m = 0; m < 4; ++m) {
            const int rowb = row0 + wr + m * 16 + (l4 << 2);
#pragma unroll
            for (int r = 0; r < 4; ++r) {
                float t = acc[m][n][r] * inv + bc;
                t = (t > 20.f) ? t : log1pf(__expf(t));
                C[(size_t)(rowb + r) * ldc + col] = t;
            }
        }
    }
}

// ---------------- fp32 vector GEMM (input projection, K=64) ----------------
__global__ __launch_bounds__(256) void gemm_in(
    const float* __restrict__ A, int lda,
    const float* __restrict__ B, int ldb,
    const float* __restrict__ bias,
    float* __restrict__ C, int ldc, int K,
    unsigned int* __restrict__ oamax)
{
    __shared__ __align__(16) float As[8][128];
    __shared__ __align__(16) float Bs[8][128];
    const int tid  = threadIdx.x;
    const int row0 = blockIdx.y << 7;
    const int col0 = blockIdx.x << 7;
    const int tx = tid & 15, ty = tid >> 4;

    float acc[8][8];
#pragma unroll
    for (int i = 0; i < 8; ++i)
#pragma unroll
        for (int j = 0; j < 8; ++j) acc[i][j] = 0.f;

    const int arow = tid >> 1;
    const int acol = (tid & 1) << 2;
    const float* Ap = A + (size_t)(row0 + arow) * lda + acol;
    const float* Bp = B + (size_t)(col0 + arow) * ldb + acol;

    for (int k0 = 0; k0 < K; k0 += 8) {
        const float4 av = *(const float4*)(Ap + k0);
        const float4 bv = *(const float4*)(Bp + k0);
        __syncthreads();
        As[acol + 0][arow] = av.x; As[acol + 1][arow] = av.y;
        As[acol + 2][arow] = av.z; As[acol + 3][arow] = av.w;
        Bs[acol + 0][arow] = bv.x; Bs[acol + 1][arow] = bv.y;
        Bs[acol + 2][arow] = bv.z; Bs[acol + 3][arow] = bv.w;
        __syncthreads();
#pragma unroll
        for (int k = 0; k < 8; ++k) {
            float a[8], b[8];
            *(float4*)&a[0] = *(const float4*)&As[k][ty << 3];
            *(float4*)&a[4] = *(const float4*)&As[k][(ty << 3) + 4];
            *(float4*)&b[0] = *(const float4*)&Bs[k][tx << 3];
            *(float4*)&b[4] = *(const float4*)&Bs[k][(tx << 3) + 4];
#pragma unroll
            for (int i = 0; i < 8; ++i)
#pragma unroll
                for (int j = 0; j < 8; ++j)
                    acc[i][j] = fmaf(a[i], b[j], acc[i][j]);
        }
    }

    float bv8[8];
#pragma unroll
    for (int j = 0; j < 8; ++j) bv8[j] = bias[col0 + (tx << 3) + j];

    float am = 0.f;
#pragma unroll
    for (int i = 0; i < 8; ++i) {
        float v[8];
#pragma unroll
        for (int j = 0; j < 8; ++j) {
            v[j] = acc[i][j] + bv8[j];
            am = fmaxf(am, fabsf(v[j]));
        }
        float* Cp = C + (size_t)(row0 + (ty << 3) + i) * ldc + col0 + (tx << 3);
        *(float4*)(Cp)     = make_float4(v[0], v[1], v[2], v[3]);
        *(float4*)(Cp + 4) = make_float4(v[4], v[5], v[6], v[7]);
    }
#pragma unroll
    for (int off = 32; off; off >>= 1) am = fmaxf(am, __shfl_down(am, off));
    if ((tid & 63) == 0) atomicMax(oamax, __float_as_uint(am));
}

// depthwise causal conv (DC=4) + bias + SiLU, float4, grid-stride, fused amax.
__global__ __launch_bounds__(256) void conv_silu_kernel(
    const float* __restrict__ xz, const float* __restrict__ cw,
    const float* __restrict__ cb, float* __restrict__ u,
    size_t total4, unsigned int* __restrict__ uamax)
{
    float am = 0.f;
    for (size_t i = (size_t)blockIdx.x * 256 + threadIdx.x; i < total4;
         i += (size_t)gridDim.x * 256) {
        const size_t e = i * 4;
        const int c = (int)(e & (DI_ - 1));
        const size_t m = e >> 10;
        const int t = (int)(m & (T_ - 1));
        const float* xr = xz + m * 2048 + c;
        const float4 zero = make_float4(0.f, 0.f, 0.f, 0.f);
        const float4 x0 = (t >= 3) ? *(const float4*)(xr - 3 * 2048) : zero;
        const float4 x1 = (t >= 2) ? *(const float4*)(xr - 2 * 2048) : zero;
        const float4 x2 = (t >= 1) ? *(const float4*)(xr - 1 * 2048) : zero;
        const float4 x3 = *(const float4*)(xr);
        const float4 cbv = *(const float4*)(cb + c);
        const float4 w0 = *(const float4*)(cw + (size_t)c * 4);
        const float4 w1 = *(const float4*)(cw + (size_t)(c + 1) * 4);
        const float4 w2 = *(const float4*)(cw + (size_t)(c + 2) * 4);
        const float4 w3 = *(const float4*)(cw + (size_t)(c + 3) * 4);
        float4 r;
        r.x = silu_f(fmaf(x3.x, w0.w, fmaf(x2.x, w0.z, fmaf(x1.x, w0.y, fmaf(x0.x, w0.x, cbv.x)))));
        r.y = silu_f(fmaf(x3.y, w1.w, fmaf(x2.y, w1.z, fmaf(x1.y, w1.y, fmaf(x0.y, w1.x, cbv.y)))));
        r.z = silu_f(fmaf(x3.z, w2.w, fmaf(x2.z, w2.z, fmaf(x1.z, w2.y, fmaf(x0.z, w2.x, cbv.z)))));
        r.w = silu_f(fmaf(x3.w, w3.w, fmaf(x2.w, w3.z, fmaf(x1.w, w3.y, fmaf(x0.w, w3.x, cbv.w)))));
        *(float4*)(u + e) = r;
        am = fmaxf(am, fmaxf(fmaxf(fabsf(r.x), fabsf(r.y)),
                             fmaxf(fabsf(r.z), fabsf(r.w))));
    }
#pragma unroll
    for (int off = 32; off; off >>= 1) am = fmaxf(am, __shfl_down(am, off));
    __shared__ float sm[4];
    if ((threadIdx.x & 63) == 0) sm[threadIdx.x >> 6] = am;
    __syncthreads();
    if (threadIdx.x == 0) {
        const float b = fmaxf(fmaxf(sm[0], sm[1]), fmaxf(sm[2], sm[3]));
        atomicMax(uamax, __float_as_uint(b));
    }
}

// -------- chunk-parallel selective scan (linear recurrence, 3 phases) -----
// Fast path: a2[n] == (n+1)*a2[0] (A_log = log(1..N) tile) -> one exp2/step.

__device__ __forceinline__ bool geo_check(const float* a2) {
    bool ok = true;
#pragma unroll
    for (int n = 1; n < N_; ++n)
        ok = ok && (fabsf(a2[n] - a2[0] * (n + 1)) <=
                    1e-5f * fmaxf(1.f, fabsf(a2[n])));
    return ok;
}

__global__ __launch_bounds__(256) void scan_pass1(
    const float* __restrict__ xz, const float* __restrict__ u,
    const float* __restrict__ dbc, const float* __restrict__ A_log_l,
    float* __restrict__ P, float* __restrict__ S)
{
    __shared__ float sB[CL_][N_];
    const int tid = threadIdx.x;
    const int b = blockIdx.x, ch = blockIdx.z;
    const int d = (blockIdx.y << 8) + tid;

    float a2[N_], Pm[N_], hs[N_];
#pragma unroll
    for (int n = 0; n < N_; ++n) {
        a2[n] = -__expf(A_log_l[d * N_ + n]) * 1.44269504f;
        Pm[n] = 1.f; hs[n] = 0.f;
    }
    const bool geo = geo_check(a2);
    for (int i = tid; i < CL_ * N_; i += 256) {
        const int tl = i >> 4, n = i & 15;
        sB[tl][n] = dbc[((size_t)b * T_ + ch * CL_ + tl) * 64 + 32 + n];
    }
    __syncthreads();

    if (geo) {
        for (int tt = 0; tt < CL_; ++tt) {
            const size_t m = (size_t)b * T_ + ch * CL_ + tt;
            const float dl = xz[m * 2048 + d];
            const float du = dl * u[m * DI_ + d];
            const float r = exp2f(dl * a2[0]);
            float dA = r;
#pragma unroll
            for (int n = 0; n < N_; ++n) {
                Pm[n] *= dA;
                hs[n] = fmaf(dA, hs[n], du * sB[tt][n]);
                dA *= r;
            }
        }
    } else {
        for (int tt = 0; tt < CL_; ++tt) {
            const size_t m = (size_t)b * T_ + ch * CL_ + tt;
            const float dl = xz[m * 2048 + d];
            const float du = dl * u[m * DI_ + d];
#pragma unroll
            for (int n = 0; n < N_; ++n) {
                const float dA = exp2f(dl * a2[n]);
                Pm[n] *= dA;
                hs[n] = fmaf(dA, hs[n], du * sB[tt][n]);
            }
        }
    }
#pragma unroll
    for (int n = 0; n < N_; ++n) {
        const size_t idx = (size_t)(((b * NCH_ + ch) * N_ + n) << 10) + d;
        P[idx] = Pm[n]; S[idx] = hs[n];
    }
}

__global__ __launch_bounds__(256) void scan_carry(
    const float* __restrict__ P, float* __restrict__ S)
{
    const size_t gid = (size_t)blockIdx.x * 256 + threadIdx.x;
    const int d = (int)(gid & 1023);
    const int n = (int)((gid >> 10) & 15);
    const int b = (int)(gid >> 14);
    float hc = 0.f;
    for (int ch = 0; ch < NCH_; ++ch) {
        const size_t idx = (size_t)(((b * NCH_ + ch) * N_ + n) << 10) + d;
        const float p = P[idx], s = S[idx];
        S[idx] = hc;
        hc = fmaf(p, hc, s);
    }
}

__global__ __launch_bounds__(256) void scan_pass3(
    float* __restrict__ xz, const float* __restrict__ u,
    const float* __restrict__ dbc, const float* __restrict__ A_log_l,
    const float* __restrict__ Dp_l, const float* __restrict__ S,
    unsigned int* __restrict__ gmax)
{
    __shared__ float sB[CL_][N_];
    __shared__ float sC[CL_][N_];
    const int tid = threadIdx.x;
    const int b = blockIdx.x, ch = blockIdx.z;
    const int d = (blockIdx.y << 8) + tid;

    float a2[N_], hs[N_];
#pragma unroll
    for (int n = 0; n < N_; ++n) {
        a2[n] = -__expf(A_log_l[d * N_ + n]) * 1.44269504f;
        hs[n] = S[(size_t)(((b * NCH_ + ch) * N_ + n) << 10) + d];
    }
    const bool geo = geo_check(a2);
    const float Dpd = Dp_l[d];
    for (int i = tid; i < CL_ * N_; i += 256) {
        const int tl = i >> 4, n = i & 15;
        const size_t base = ((size_t)b * T_ + ch * CL_ + tl) * 64;
        sB[tl][n] = dbc[base + 32 + n];
        sC[tl][n] = dbc[base + 48 + n];
    }
    __syncthreads();

    float gm = 0.f;
    if (geo) {
        for (int tt = 0; tt < CL_; ++tt) {
            const size_t m = (size_t)b * T_ + ch * CL_ + tt;
            const float dl = xz[m * 2048 + d];
            const float uv = u[m * DI_ + d];
            const float du = dl * uv;
            const float r = exp2f(dl * a2[0]);
            float dA = r;
            float yv = 0.f;
#pragma unroll
            for (int n = 0; n < N_; ++n) {
                hs[n] = fmaf(dA, hs[n], du * sB[tt][n]);
                yv = fmaf(hs[n], sC[tt][n], yv);
                dA *= r;
            }
            yv = fmaf(uv, Dpd, yv);
            const float g = yv * silu_f(xz[m * 2048 + DI_ + d]);
            xz[m * 2048 + d] = g;
            gm = fmaxf(gm, fabsf(g));
        }
    } else {
        for (int tt = 0; tt < CL_; ++tt) {
            const size_t m = (size_t)b * T_ + ch * CL_ + tt;
            const float dl = xz[m * 2048 + d];
            const float uv = u[m * DI_ + d];
            const float du = dl * uv;
            float yv = 0.f;
#pragma unroll
            for (int n = 0; n < N_; ++n) {
                const float dA = exp2f(dl * a2[n]);
                hs[n] = fmaf(dA, hs[n], du * sB[tt][n]);
                yv = fmaf(hs[n], sC[tt][n], yv);
            }
            yv = fmaf(uv, Dpd, yv);
            const float g = yv * silu_f(xz[m * 2048 + DI_ + d]);
            xz[m * 2048 + d] = g;
            gm = fmaxf(gm, fabsf(g));
        }
    }
#pragma unroll
    for (int off = 32; off; off >>= 1) gm = fmaxf(gm, __shfl_down(gm, off));
    if ((tid & 63) == 0) atomicMax(gmax, __float_as_uint(gm));
}

extern "C" void kernel_launch(void* const* d_in, const int* in_sizes, int n_in,
                              void* d_out, int out_size, void* d_ws, size_t ws_size,
                              hipStream_t stream) {
    const float* x     = (const float*)d_in[0];
    const float* Wi    = (const float*)d_in[1];
    const float* bi    = (const float*)d_in[2];
    const float* Win   = (const float*)d_in[3];
    const float* convw = (const float*)d_in[4];
    const float* convb = (const float*)d_in[5];
    const float* Wx    = (const float*)d_in[6];
    const float* Wdt   = (const float*)d_in[7];
    const float* bdt   = (const float*)d_in[8];
    const float* A_log = (const float*)d_in[9];
    const float* Dp    = (const float*)d_in[10];
    const float* Wout  = (const float*)d_in[11];
    const float* Wo    = (const float*)d_in[12];
    const float* bo    = (const float*)d_in[13];
    float* out = (float*)d_out;

    // Per-row f32: xz 2048 + u 1024 + dbc 64 + hPS 512 (h | scan P,S) = 3648.
    // h and P/S share the hPS region: h is dead after the xz GEMM reads it
    // (start of layer); P/S live only mid-layer (scan); the Wout GEMM writes
    // the next h there after P/S are dead. Extras: f16 weights + 32 slots.
    const size_t rowf = 3648;
    const size_t wextra =
        (3 * 1048576 + 3 * 524288 + 65536 + 3 * 65536 + 3 * 32768) / 2 + 32;
    int CB = BB_;
    while (CB > 1 && ((size_t)CB * T_ * rowf + wextra) * sizeof(float) > ws_size) CB >>= 1;
    const size_t Mc = (size_t)CB * T_;

    const dim3 blk(256);
    const int rowTiles = (int)(Mc / 128);

    float* ws   = (float*)d_ws;
    float* xz   = ws;                    // Mc*2048 (xin/delta/g | z)
    float* u    = xz + Mc * 2048;        // Mc*1024
    float* dbc  = u  + Mc * 1024;        // Mc*64
    float* hPS  = dbc + Mc * 64;         // Mc*512: h (ld 512) / scan P,S
    float* hb   = hPS;
    float* Pbuf = hPS;                               // Mc*128 floats
    float* Sbuf = hPS + (size_t)CB * NCH_ * N_ * DI_;
    unsigned short* WinH  = (unsigned short*)(hPS + Mc * 512);
    unsigned short* WoutH = WinH + 3 * 1048576;
    unsigned short* WoH   = WoutH + 3 * 524288;
    unsigned short* WxH   = WoH + 65536;
    unsigned short* WdtH  = WxH + 3 * 65536;
    unsigned int* scales  = (unsigned int*)(WdtH + 3 * 32768);
    // slots: 0-2 Win, 3-5 Wout, 6 Wo, 7-9 Wx, 10-12 Wdt,
    //        13..16 h[0..3], 17-19 g[l], 20-22 u[l], 23-25 dt[l]

    hipMemsetAsync(scales, 0, 32 * sizeof(unsigned int), stream);

    amax_all<<<dim3(128, 1, 13), blk, 0, stream>>>(Win, Wout, Wx, Wdt, Wo, scales);
    cast_all<<<dim3(64, 1, 13), blk, 0, stream>>>(
        Win, Wout, Wx, Wdt, Wo, WinH, WoutH, WxH, WdtH, WoH, scales);

    for (int c = 0; c < BB_ / CB; ++c) {
        const float* x_c = x + (size_t)c * Mc * DIN_;
        float* out_c     = out + (size_t)c * Mc * DOUT_;

        hipMemsetAsync(scales + 13, 0, 13 * sizeof(unsigned int), stream);

        // h = x @ Wi.T + bi  (fp32, K=64) -> hb (ld 512), amax -> h[0]
        gemm_in<<<dim3(D_ / 128, rowTiles), blk, 0, stream>>>(
            x_c, DIN_, Wi, DIN_, bi, hb, D_, DIN_, scales + 13);

        for (int l = 0; l < L_; ++l) {
            const float* cw_l   = convw + (size_t)l * DI_ * DC_;
            const float* cb_l   = convb + (size_t)l * DI_;
            const float* bdt_l  = bdt  + (size_t)l * DI_;
            const float* Alog_l = A_log + (size_t)l * DI_ * N_;
            const float* Dp_l   = Dp   + (size_t)l * DI_;

            // xz = h @ Win.T  (A fp32 staged-cast, f16 MFMA, pipelined)
            gemm_f32a_t128<0><<<dim3(2048 / 128, rowTiles), blk, 0, stream>>>(
                hb, D_, WinH + (size_t)l * 1048576, D_, nullptr,
                xz, 2048, D_, scales + 13 + l, scales + l, nullptr);

            // u = silu(causal_dwconv(xin) + cb), fused u amax
            conv_silu_kernel<<<dim3(2048), blk, 0, stream>>>(
                xz, cw_l, cb_l, u, Mc * DI_ / 4, scales + 20 + l);

            // dbc = u @ Wx.T  (f16 MFMA 128x64) + dt amax
            gemm_f16u_t64n<<<dim3(1, rowTiles), blk, 0, stream>>>(
                u, DI_, WxH + (size_t)l * 65536, DI_, dbc, 64, DI_,
                scales + 20 + l, scales + 7 + l, scales + 23 + l);

            // delta = softplus(dt @ Wdt.T + bdt) -> xz[:, :1024] (MFMA K=32)
            gemm_delta<<<dim3(DI_ / 128, rowTiles), blk, 0, stream>>>(
                dbc, WdtH + (size_t)l * 32768, bdt_l, xz, 2048,
                scales + 23 + l, scales + 10 + l);

            // chunk-parallel scan; g -> xz[:, :1024], amax -> g[l]
            // (h is dead now; scan P/S reuse the hPS region)
            scan_pass1<<<dim3(CB, DI_ / 256, NCH_), blk, 0, stream>>>(
                xz, u, dbc, Alog_l, Pbuf, Sbuf);
            scan_carry<<<dim3(CB * 64), blk, 0, stream>>>(Pbuf, Sbuf);
            scan_pass3<<<dim3(CB, DI_ / 256, NCH_), blk, 0, stream>>>(
                xz, u, dbc, Alog_l, Dp_l, Sbuf, scales + 17 + l);

            // h = g @ Wout.T  (A fp32 staged-cast) -> hb (P/S dead)
            gemm_f32a_t128<0><<<dim3(D_ / 128, rowTiles), blk, 0, stream>>>(
                xz, 2048, WoutH + (size_t)l * 524288, DI_, nullptr,
                hb, D_, DI_, scales + 17 + l, scales + 3 + l, scales + 14 + l);
        }

        // out = tanh(h @ Wo.T + bo)
        gemm_f32a_t128<3><<<dim3(DOUT_ / 128, rowTiles), blk, 0, stream>>>(
            hb, D_, WoH, D_, bo, out_c, DOUT_, D_,
            scales + 16, scales + 6, nullptr);
    }
}

// Round 13
// 2693.468 us; speedup vs baseline: 1.1375x; 1.1375x over previous
//
#include <hip/hip_runtime.h>
#include <hip/hip_bf16.h>

#define BB_ 16
#define T_ 2048
#define DIN_ 64
#define D_ 512
#define DI_ 1024
#define N_ 16
#define DC_ 4
#define R_ 32
#define L_ 3
#define DOUT_ 128
#define CL_ 128              // scan chunk length
#define NCH_ (T_ / CL_)      // 16 chunks

typedef __attribute__((ext_vector_type(8))) _Float16 f16x8;
typedef __attribute__((ext_vector_type(4))) float f32x4;

__device__ __forceinline__ float silu_f(float x) { return x / (1.f + __expf(-x)); }

// fast branch-free softplus: log(1+e^t) = max(t,0) + log(1+e^-|t|)
__device__ __forceinline__ float softplus_f(float t) {
    return fmaxf(t, 0.f) + __logf(1.f + __expf(-fabsf(t)));
}

__device__ __forceinline__ unsigned short f2h(float f) {
    union { _Float16 h; unsigned short u; } c;
    c.h = (_Float16)f;   // RNE
    return c.u;
}

// decode scale from amax bits: s = 2^(11 - e), so s*amax lands in [2^11, 2^12)
__device__ __forceinline__ float decode_scale(unsigned int bits) {
    if (bits == 0u) return 1.f;
    const int E = (int)(bits >> 23) & 0xFF;
    return __uint_as_float((unsigned)(265 - E) << 23);
}

__device__ __forceinline__ uint4 pack8(float4 lo, float4 hi, float s) {
    union { uint4 u; unsigned short h[8]; } r;
    r.h[0] = f2h(lo.x * s); r.h[1] = f2h(lo.y * s);
    r.h[2] = f2h(lo.z * s); r.h[3] = f2h(lo.w * s);
    r.h[4] = f2h(hi.x * s); r.h[5] = f2h(hi.y * s);
    r.h[6] = f2h(hi.z * s); r.h[7] = f2h(hi.w * s);
    return r.u;
}

// regions: 0-2 Win[l] (262144 f4), 3-5 Wout[l] (131072), 6 Wo (16384),
// 7-9 Wx[l] (16384), 10-12 Wdt[l] (8192). slot == region.
__device__ __forceinline__ const float* wregion(
    int r, const float* Win, const float* Wout, const float* Wx,
    const float* Wdt, const float* Wo, size_t* n4)
{
    if (r < 3)       { *n4 = 262144; return Win  + (size_t)r * 1048576; }
    else if (r < 6)  { *n4 = 131072; return Wout + (size_t)(r - 3) * 524288; }
    else if (r == 6) { *n4 = 16384;  return Wo; }
    else if (r < 10) { *n4 = 16384;  return Wx  + (size_t)(r - 7) * 65536; }
    else             { *n4 = 8192;   return Wdt + (size_t)(r - 10) * 32768; }
}

__global__ __launch_bounds__(256) void amax_all(
    const float* __restrict__ Win, const float* __restrict__ Wout,
    const float* __restrict__ Wx, const float* __restrict__ Wdt,
    const float* __restrict__ Wo, unsigned int* __restrict__ scales)
{
    size_t n4;
    const float* p = wregion(blockIdx.z, Win, Wout, Wx, Wdt, Wo, &n4);
    float m = 0.f;
    for (size_t i = (size_t)blockIdx.x * 256 + threadIdx.x; i < n4;
         i += (size_t)gridDim.x * 256) {
        const float4 v = ((const float4*)p)[i];
        m = fmaxf(m, fmaxf(fmaxf(fabsf(v.x), fabsf(v.y)),
                           fmaxf(fabsf(v.z), fabsf(v.w))));
    }
#pragma unroll
    for (int off = 32; off; off >>= 1) m = fmaxf(m, __shfl_down(m, off));
    __shared__ float sm[4];
    if ((threadIdx.x & 63) == 0) sm[threadIdx.x >> 6] = m;
    __syncthreads();
    if (threadIdx.x == 0) {
        const float b = fmaxf(fmaxf(sm[0], sm[1]), fmaxf(sm[2], sm[3]));
        atomicMax(scales + blockIdx.z, __float_as_uint(b));
    }
}

__global__ __launch_bounds__(256) void cast_all(
    const float* __restrict__ Win, const float* __restrict__ Wout,
    const float* __restrict__ Wx, const float* __restrict__ Wdt,
    const float* __restrict__ Wo,
    unsigned short* __restrict__ WinH, unsigned short* __restrict__ WoutH,
    unsigned short* __restrict__ WxH, unsigned short* __restrict__ WdtH,
    unsigned short* __restrict__ WoH,
    const unsigned int* __restrict__ scales)
{
    const int r = blockIdx.z;
    size_t n4;
    const float* p = wregion(r, Win, Wout, Wx, Wdt, Wo, &n4);
    unsigned short* o;
    if (r < 3)       o = WinH  + (size_t)r * 1048576;
    else if (r < 6)  o = WoutH + (size_t)(r - 3) * 524288;
    else if (r == 6) o = WoH;
    else if (r < 10) o = WxH   + (size_t)(r - 7) * 65536;
    else             o = WdtH  + (size_t)(r - 10) * 32768;
    const float s = decode_scale(scales[r]);
    for (size_t i = (size_t)blockIdx.x * 256 + threadIdx.x; i < n4;
         i += (size_t)gridDim.x * 256) {
        const float4 v = ((const float4*)p)[i];
        ((ushort4*)o)[i] = make_ushort4(f2h(v.x * s), f2h(v.y * s),
                                        f2h(v.z * s), f2h(v.w * s));
    }
}

// ------- scaled MFMA GEMM, A fp32 (cast during LDS staging), B f16 --------
// 128x128 tile, BK=32, 4 waves (2x2), per-wave 64x64 = 4x4 frags of 16x16x32.
// Pipelined: next-step global loads issued before MFMA cluster.
// ACT: 0 = none, 3 = +bias tanh. Output fp32 (+ optional amax).
// NOTE: C must NOT alias A (blocks read A rows outside their C tile).
template<int ACT>
__global__ __launch_bounds__(256) void gemm_f32a_t128(
    const float* __restrict__ A, int lda,
    const unsigned short* __restrict__ B, int ldb,
    const float* __restrict__ bias,
    float* __restrict__ C, int ldc, int K,
    const unsigned int* __restrict__ sa, const unsigned int* __restrict__ sb,
    unsigned int* __restrict__ oamax)
{
    __shared__ __align__(16) unsigned short As[128 * 32];
    __shared__ __align__(16) unsigned short Bs[128 * 32];
    const int tid  = threadIdx.x;
    const int lane = tid & 63;
    const int w    = tid >> 6;
    const int wr   = (w >> 1) << 6;
    const int wc   = (w & 1) << 6;
    const int l15  = lane & 15, l4 = lane >> 4;
    const int row0 = blockIdx.y << 7, col0 = blockIdx.x << 7;
    const int tq   = tid >> 2;
    const int tr   = (tid & 3) << 3;

    const float sA  = decode_scale(*sa);
    const float inv = (1.f / sA) * (1.f / decode_scale(*sb));

    const float* Ar0 = A + (size_t)(row0 + tq) * lda + tr;
    const float* Ar1 = A + (size_t)(row0 + 64 + tq) * lda + tr;
    const unsigned short* Br0 = B + (size_t)(col0 + tq) * ldb + tr;
    const unsigned short* Br1 = B + (size_t)(col0 + 64 + tq) * ldb + tr;

    f32x4 acc[4][4];
#pragma unroll
    for (int m = 0; m < 4; ++m)
#pragma unroll
        for (int n = 0; n < 4; ++n) acc[m][n] = (f32x4){0.f, 0.f, 0.f, 0.f};

    float4 a0lo = *(const float4*)(Ar0), a0hi = *(const float4*)(Ar0 + 4);
    float4 a1lo = *(const float4*)(Ar1), a1hi = *(const float4*)(Ar1 + 4);
    uint4  bv0  = *(const uint4*)(Br0);
    uint4  bv1  = *(const uint4*)(Br1);

    for (int k0 = 0; k0 < K; k0 += 32) {
        __syncthreads();
        *(uint4*)&As[tq * 32 + tr]        = pack8(a0lo, a0hi, sA);
        *(uint4*)&As[(64 + tq) * 32 + tr] = pack8(a1lo, a1hi, sA);
        *(uint4*)&Bs[tq * 32 + tr]        = bv0;
        *(uint4*)&Bs[(64 + tq) * 32 + tr] = bv1;
        __syncthreads();

        if (k0 + 32 < K) {
            a0lo = *(const float4*)(Ar0 + k0 + 32);
            a0hi = *(const float4*)(Ar0 + k0 + 36);
            a1lo = *(const float4*)(Ar1 + k0 + 32);
            a1hi = *(const float4*)(Ar1 + k0 + 36);
            bv0  = *(const uint4*)(Br0 + k0 + 32);
            bv1  = *(const uint4*)(Br1 + k0 + 32);
        }

        f16x8 af[4], bfr[4];
#pragma unroll
        for (int m = 0; m < 4; ++m)
            af[m] = *(const f16x8*)&As[(wr + m * 16 + l15) * 32 + l4 * 8];
#pragma unroll
        for (int n = 0; n < 4; ++n)
            bfr[n] = *(const f16x8*)&Bs[(wc + n * 16 + l15) * 32 + l4 * 8];
#pragma unroll
        for (int m = 0; m < 4; ++m)
#pragma unroll
            for (int n = 0; n < 4; ++n)
                acc[m][n] = __builtin_amdgcn_mfma_f32_16x16x32_f16(
                    af[m], bfr[n], acc[m][n], 0, 0, 0);
    }

    float am = 0.f;
#pragma unroll
    for (int n = 0; n < 4; ++n) {
        const int col = col0 + wc + n * 16 + l15;
        float bc = 0.f;
        if (ACT == 3) bc = bias[col];
#pragma unroll
        for (int m = 0; m < 4; ++m) {
            const int rowb = row0 + wr + m * 16 + (l4 << 2);
#pragma unroll
            for (int r = 0; r < 4; ++r) {
                float v = acc[m][n][r] * inv;
                if (ACT == 3) v = tanhf(v + bc);
                C[(size_t)(rowb + r) * ldc + col] = v;
                am = fmaxf(am, fabsf(v));
            }
        }
    }
    if (oamax) {
#pragma unroll
        for (int off = 32; off; off >>= 1) am = fmaxf(am, __shfl_down(am, off));
        if (lane == 0) atomicMax(oamax, __float_as_uint(am));
    }
}

// ---- dbc GEMM: A fp32 u (staged cast), B f16 Wx. 128x64 tile, pipelined.
// Also emits amax over output cols 0..31 (= dt) for the delta GEMM.
__global__ __launch_bounds__(256) void gemm_f16u_t64n(
    const float* __restrict__ A, int lda,
    const unsigned short* __restrict__ B, int ldb,
    float* __restrict__ C, int ldc, int K,
    const unsigned int* __restrict__ sa, const unsigned int* __restrict__ sb,
    unsigned int* __restrict__ dtmax)
{
    __shared__ __align__(16) unsigned short As[128 * 32];
    __shared__ __align__(16) unsigned short Bs[64 * 32];
    const int tid  = threadIdx.x;
    const int lane = tid & 63;
    const int w    = tid >> 6;
    const int l15  = lane & 15, l4 = lane >> 4;
    const int row0 = blockIdx.y << 7;
    const int tq   = tid >> 2;
    const int tr   = (tid & 3) << 3;

    const float sA  = decode_scale(*sa);
    const float inv = (1.f / sA) * (1.f / decode_scale(*sb));

    const float* Ar0 = A + (size_t)(row0 + tq) * lda + tr;
    const float* Ar1 = A + (size_t)(row0 + 64 + tq) * lda + tr;
    const unsigned short* Br = B + (size_t)tq * ldb + tr;   // 64 rows

    f32x4 acc[2][4];
#pragma unroll
    for (int m = 0; m < 2; ++m)
#pragma unroll
        for (int n = 0; n < 4; ++n) acc[m][n] = (f32x4){0.f, 0.f, 0.f, 0.f};

    float4 a0lo = *(const float4*)(Ar0), a0hi = *(const float4*)(Ar0 + 4);
    float4 a1lo = *(const float4*)(Ar1), a1hi = *(const float4*)(Ar1 + 4);
    uint4  bv   = *(const uint4*)(Br);

    for (int k0 = 0; k0 < K; k0 += 32) {
        __syncthreads();
        *(uint4*)&As[tq * 32 + tr]        = pack8(a0lo, a0hi, sA);
        *(uint4*)&As[(64 + tq) * 32 + tr] = pack8(a1lo, a1hi, sA);
        *(uint4*)&Bs[tq * 32 + tr]        = bv;
        __syncthreads();

        if (k0 + 32 < K) {
            a0lo = *(const float4*)(Ar0 + k0 + 32);
            a0hi = *(const float4*)(Ar0 + k0 + 36);
            a1lo = *(const float4*)(Ar1 + k0 + 32);
            a1hi = *(const float4*)(Ar1 + k0 + 36);
            bv   = *(const uint4*)(Br  + k0 + 32);
        }

        f16x8 af[2], bfr[4];
#pragma unroll
        for (int m = 0; m < 2; ++m)
            af[m] = *(const f16x8*)&As[(w * 32 + m * 16 + l15) * 32 + l4 * 8];
#pragma unroll
        for (int n = 0; n < 4; ++n)
            bfr[n] = *(const f16x8*)&Bs[(n * 16 + l15) * 32 + l4 * 8];
#pragma unroll
        for (int m = 0; m < 2; ++m)
#pragma unroll
            for (int n = 0; n < 4; ++n)
                acc[m][n] = __builtin_amdgcn_mfma_f32_16x16x32_f16(
                    af[m], bfr[n], acc[m][n], 0, 0, 0);
    }

    float am = 0.f;
#pragma unroll
    for (int n = 0; n < 4; ++n) {
        const int col = n * 16 + l15;
#pragma unroll
        for (int m = 0; m < 2; ++m) {
            const int rowb = row0 + w * 32 + m * 16 + (l4 << 2);
#pragma unroll
            for (int r = 0; r < 4; ++r) {
                const float v = acc[m][n][r] * inv;
                C[(size_t)(rowb + r) * ldc + col] = v;
                if (n < 2) am = fmaxf(am, fabsf(v));   // dt cols 0..31
            }
        }
    }
#pragma unroll
    for (int off = 32; off; off >>= 1) am = fmaxf(am, __shfl_down(am, off));
    if (lane == 0) atomicMax(dtmax, __float_as_uint(am));
}

// ---- delta GEMM (K=32, single MFMA step): delta = softplus(dt@Wdt.T + bdt)
// A = dbc fp32 (lda 64, cols 0..31, staged cast), B = Wdt f16 (ldb 32).
// Output fp32 strided (ldc 2048) into the xin slot of xz.
__global__ __launch_bounds__(256) void gemm_delta(
    const float* __restrict__ A,
    const unsigned short* __restrict__ B,
    const float* __restrict__ bias,
    float* __restrict__ C, int ldc,
    const unsigned int* __restrict__ sa, const unsigned int* __restrict__ sb)
{
    __shared__ __align__(16) unsigned short As[128 * 32];
    __shared__ __align__(16) unsigned short Bs[128 * 32];
    const int tid  = threadIdx.x;
    const int lane = tid & 63;
    const int w    = tid >> 6;
    const int wr   = (w >> 1) << 6;
    const int wc   = (w & 1) << 6;
    const int l15  = lane & 15, l4 = lane >> 4;
    const int row0 = blockIdx.y << 7, col0 = blockIdx.x << 7;
    const int tq   = tid >> 2;
    const int tr   = (tid & 3) << 3;

    const float sA  = decode_scale(*sa);
    const float inv = (1.f / sA) * (1.f / decode_scale(*sb));

    const float* Ar0 = A + (size_t)(row0 + tq) * 64 + tr;
    const float* Ar1 = A + (size_t)(row0 + 64 + tq) * 64 + tr;
    const float4 a0lo = *(const float4*)(Ar0), a0hi = *(const float4*)(Ar0 + 4);
    const float4 a1lo = *(const float4*)(Ar1), a1hi = *(const float4*)(Ar1 + 4);
    const uint4 bv0 = *(const uint4*)(B + (size_t)(col0 + tq) * 32 + tr);
    const uint4 bv1 = *(const uint4*)(B + (size_t)(col0 + 64 + tq) * 32 + tr);

    *(uint4*)&As[tq * 32 + tr]        = pack8(a0lo, a0hi, sA);
    *(uint4*)&As[(64 + tq) * 32 + tr] = pack8(a1lo, a1hi, sA);
    *(uint4*)&Bs[tq * 32 + tr]        = bv0;
    *(uint4*)&Bs[(64 + tq) * 32 + tr] = bv1;
    __syncthreads();

    f32x4 acc[4][4];
#pragma unroll
    for (int m = 0; m < 4; ++m)
#pragma unroll
        for (int n = 0; n < 4; ++n) acc[m][n] = (f32x4){0.f, 0.f, 0.f, 0.f};

    f16x8 af[4], bfr[4];
#pragma unroll
    for (int m = 0; m < 4; ++m)
        af[m] = *(const f16x8*)&As[(wr + m * 16 + l15) * 32 + l4 * 8];
#pragma unroll
    for (int n = 0; n < 4; ++n)
        bfr[n] = *(const f16x8*)&Bs[(wc + n * 16 + l15) * 32 + l4 * 8];
#pragma unroll
    for (int m = 0; m < 4; ++m)
#pragma unroll
        for (int n = 0; n < 4; ++n)
            acc[m][n] = __builtin_amdgcn_mfma_f32_16x16x32_f16(
                af[m], bfr[n], acc[m][n], 0, 0, 0);

#pragma unroll
    for (int n = 0; n < 4; ++n) {
        const int col = col0 + wc + n * 16 + l15;
        const float bc = bias[col];
#pragma unroll
        for (int m = 0; m < 4; ++m) {
            const int rowb = row0 + wr + m * 16 + (l4 << 2);
#pragma unroll
            for (int r = 0; r < 4; ++r) {
                const float t = acc[m][n][r] * inv + bc;
                C[(size_t)(rowb + r) * ldc + col] = softplus_f(t);
            }
        }
    }
}

// ---------------- fp32 vector GEMM (input projection, K=64) ----------------
__global__ __launch_bounds__(256) void gemm_in(
    const float* __restrict__ A, int lda,
    const float* __restrict__ B, int ldb,
    const float* __restrict__ bias,
    float* __restrict__ C, int ldc, int K,
    unsigned int* __restrict__ oamax)
{
    __shared__ __align__(16) float As[8][128];
    __shared__ __align__(16) float Bs[8][128];
    const int tid  = threadIdx.x;
    const int row0 = blockIdx.y << 7;
    const int col0 = blockIdx.x << 7;
    const int tx = tid & 15, ty = tid >> 4;

    float acc[8][8];
#pragma unroll
    for (int i = 0; i < 8; ++i)
#pragma unroll
        for (int j = 0; j < 8; ++j) acc[i][j] = 0.f;

    const int arow = tid >> 1;
    const int acol = (tid & 1) << 2;
    const float* Ap = A + (size_t)(row0 + arow) * lda + acol;
    const float* Bp = B + (size_t)(col0 + arow) * ldb + acol;

    for (int k0 = 0; k0 < K; k0 += 8) {
        const float4 av = *(const float4*)(Ap + k0);
        const float4 bv = *(const float4*)(Bp + k0);
        __syncthreads();
        As[acol + 0][arow] = av.x; As[acol + 1][arow] = av.y;
        As[acol + 2][arow] = av.z; As[acol + 3][arow] = av.w;
        Bs[acol + 0][arow] = bv.x; Bs[acol + 1][arow] = bv.y;
        Bs[acol + 2][arow] = bv.z; Bs[acol + 3][arow] = bv.w;
        __syncthreads();
#pragma unroll
        for (int k = 0; k < 8; ++k) {
            float a[8], b[8];
            *(float4*)&a[0] = *(const float4*)&As[k][ty << 3];
            *(float4*)&a[4] = *(const float4*)&As[k][(ty << 3) + 4];
            *(float4*)&b[0] = *(const float4*)&Bs[k][tx << 3];
            *(float4*)&b[4] = *(const float4*)&Bs[k][(tx << 3) + 4];
#pragma unroll
            for (int i = 0; i < 8; ++i)
#pragma unroll
                for (int j = 0; j < 8; ++j)
                    acc[i][j] = fmaf(a[i], b[j], acc[i][j]);
        }
    }

    float bv8[8];
#pragma unroll
    for (int j = 0; j < 8; ++j) bv8[j] = bias[col0 + (tx << 3) + j];

    float am = 0.f;
#pragma unroll
    for (int i = 0; i < 8; ++i) {
        float v[8];
#pragma unroll
        for (int j = 0; j < 8; ++j) {
            v[j] = acc[i][j] + bv8[j];
            am = fmaxf(am, fabsf(v[j]));
        }
        float* Cp = C + (size_t)(row0 + (ty << 3) + i) * ldc + col0 + (tx << 3);
        *(float4*)(Cp)     = make_float4(v[0], v[1], v[2], v[3]);
        *(float4*)(Cp + 4) = make_float4(v[4], v[5], v[6], v[7]);
    }
#pragma unroll
    for (int off = 32; off; off >>= 1) am = fmaxf(am, __shfl_down(am, off));
    if ((tid & 63) == 0) atomicMax(oamax, __float_as_uint(am));
}

// depthwise causal conv (DC=4) + bias + SiLU, float4, grid-stride, fused amax.
__global__ __launch_bounds__(256) void conv_silu_kernel(
    const float* __restrict__ xz, const float* __restrict__ cw,
    const float* __restrict__ cb, float* __restrict__ u,
    size_t total4, unsigned int* __restrict__ uamax)
{
    float am = 0.f;
    for (size_t i = (size_t)blockIdx.x * 256 + threadIdx.x; i < total4;
         i += (size_t)gridDim.x * 256) {
        const size_t e = i * 4;
        const int c = (int)(e & (DI_ - 1));
        const size_t m = e >> 10;
        const int t = (int)(m & (T_ - 1));
        const float* xr = xz + m * 2048 + c;
        const float4 zero = make_float4(0.f, 0.f, 0.f, 0.f);
        const float4 x0 = (t >= 3) ? *(const float4*)(xr - 3 * 2048) : zero;
        const float4 x1 = (t >= 2) ? *(const float4*)(xr - 2 * 2048) : zero;
        const float4 x2 = (t >= 1) ? *(const float4*)(xr - 1 * 2048) : zero;
        const float4 x3 = *(const float4*)(xr);
        const float4 cbv = *(const float4*)(cb + c);
        const float4 w0 = *(const float4*)(cw + (size_t)c * 4);
        const float4 w1 = *(const float4*)(cw + (size_t)(c + 1) * 4);
        const float4 w2 = *(const float4*)(cw + (size_t)(c + 2) * 4);
        const float4 w3 = *(const float4*)(cw + (size_t)(c + 3) * 4);
        float4 r;
        r.x = silu_f(fmaf(x3.x, w0.w, fmaf(x2.x, w0.z, fmaf(x1.x, w0.y, fmaf(x0.x, w0.x, cbv.x)))));
        r.y = silu_f(fmaf(x3.y, w1.w, fmaf(x2.y, w1.z, fmaf(x1.y, w1.y, fmaf(x0.y, w1.x, cbv.y)))));
        r.z = silu_f(fmaf(x3.z, w2.w, fmaf(x2.z, w2.z, fmaf(x1.z, w2.y, fmaf(x0.z, w2.x, cbv.z)))));
        r.w = silu_f(fmaf(x3.w, w3.w, fmaf(x2.w, w3.z, fmaf(x1.w, w3.y, fmaf(x0.w, w3.x, cbv.w)))));
        *(float4*)(u + e) = r;
        am = fmaxf(am, fmaxf(fmaxf(fabsf(r.x), fabsf(r.y)),
                             fmaxf(fabsf(r.z), fabsf(r.w))));
    }
#pragma unroll
    for (int off = 32; off; off >>= 1) am = fmaxf(am, __shfl_down(am, off));
    __shared__ float sm[4];
    if ((threadIdx.x & 63) == 0) sm[threadIdx.x >> 6] = am;
    __syncthreads();
    if (threadIdx.x == 0) {
        const float b = fmaxf(fmaxf(sm[0], sm[1]), fmaxf(sm[2], sm[3]));
        atomicMax(uamax, __float_as_uint(b));
    }
}

// -------- chunk-parallel selective scan (linear recurrence, 3 phases) -----
// Fast path: a2[n] == (n+1)*a2[0] (A_log = log(1..N) tile) -> one exp2/step.

__device__ __forceinline__ bool geo_check(const float* a2) {
    bool ok = true;
#pragma unroll
    for (int n = 1; n < N_; ++n)
        ok = ok && (fabsf(a2[n] - a2[0] * (n + 1)) <=
                    1e-5f * fmaxf(1.f, fabsf(a2[n])));
    return ok;
}

__global__ __launch_bounds__(256) void scan_pass1(
    const float* __restrict__ xz, const float* __restrict__ u,
    const float* __restrict__ dbc, const float* __restrict__ A_log_l,
    float* __restrict__ P, float* __restrict__ S)
{
    __shared__ float sB[CL_][N_];
    const int tid = threadIdx.x;
    const int b = blockIdx.x, ch = blockIdx.z;
    const int d = (blockIdx.y << 8) + tid;

    float a2[N_], Pm[N_], hs[N_];
#pragma unroll
    for (int n = 0; n < N_; ++n) {
        a2[n] = -__expf(A_log_l[d * N_ + n]) * 1.44269504f;
        Pm[n] = 1.f; hs[n] = 0.f;
    }
    const bool geo = geo_check(a2);
    for (int i = tid; i < CL_ * N_; i += 256) {
        const int tl = i >> 4, n = i & 15;
        sB[tl][n] = dbc[((size_t)b * T_ + ch * CL_ + tl) * 64 + 32 + n];
    }
    __syncthreads();

    if (geo) {
        for (int tt = 0; tt < CL_; ++tt) {
            const size_t m = (size_t)b * T_ + ch * CL_ + tt;
            const float dl = xz[m * 2048 + d];
            const float du = dl * u[m * DI_ + d];
            const float r = exp2f(dl * a2[0]);
            float dA = r;
#pragma unroll
            for (int n = 0; n < N_; ++n) {
                Pm[n] *= dA;
                hs[n] = fmaf(dA, hs[n], du * sB[tt][n]);
                dA *= r;
            }
        }
    } else {
        for (int tt = 0; tt < CL_; ++tt) {
            const size_t m = (size_t)b * T_ + ch * CL_ + tt;
            const float dl = xz[m * 2048 + d];
            const float du = dl * u[m * DI_ + d];
#pragma unroll
            for (int n = 0; n < N_; ++n) {
                const float dA = exp2f(dl * a2[n]);
                Pm[n] *= dA;
                hs[n] = fmaf(dA, hs[n], du * sB[tt][n]);
            }
        }
    }
#pragma unroll
    for (int n = 0; n < N_; ++n) {
        const size_t idx = (size_t)(((b * NCH_ + ch) * N_ + n) << 10) + d;
        P[idx] = Pm[n]; S[idx] = hs[n];
    }
}

__global__ __launch_bounds__(256) void scan_carry(
    const float* __restrict__ P, float* __restrict__ S)
{
    const size_t gid = (size_t)blockIdx.x * 256 + threadIdx.x;
    const int d = (int)(gid & 1023);
    const int n = (int)((gid >> 10) & 15);
    const int b = (int)(gid >> 14);
    float hc = 0.f;
    for (int ch = 0; ch < NCH_; ++ch) {
        const size_t idx = (size_t)(((b * NCH_ + ch) * N_ + n) << 10) + d;
        const float p = P[idx], s = S[idx];
        S[idx] = hc;
        hc = fmaf(p, hc, s);
    }
}

__global__ __launch_bounds__(256) void scan_pass3(
    float* __restrict__ xz, const float* __restrict__ u,
    const float* __restrict__ dbc, const float* __restrict__ A_log_l,
    const float* __restrict__ Dp_l, const float* __restrict__ S,
    unsigned int* __restrict__ gmax)
{
    __shared__ float sB[CL_][N_];
    __shared__ float sC[CL_][N_];
    const int tid = threadIdx.x;
    const int b = blockIdx.x, ch = blockIdx.z;
    const int d = (blockIdx.y << 8) + tid;

    float a2[N_], hs[N_];
#pragma unroll
    for (int n = 0; n < N_; ++n) {
        a2[n] = -__expf(A_log_l[d * N_ + n]) * 1.44269504f;
        hs[n] = S[(size_t)(((b * NCH_ + ch) * N_ + n) << 10) + d];
    }
    const bool geo = geo_check(a2);
    const float Dpd = Dp_l[d];
    for (int i = tid; i < CL_ * N_; i += 256) {
        const int tl = i >> 4, n = i & 15;
        const size_t base = ((size_t)b * T_ + ch * CL_ + tl) * 64;
        sB[tl][n] = dbc[base + 32 + n];
        sC[tl][n] = dbc[base + 48 + n];
    }
    __syncthreads();

    float gm = 0.f;
    if (geo) {
        for (int tt = 0; tt < CL_; ++tt) {
            const size_t m = (size_t)b * T_ + ch * CL_ + tt;
            const float dl = xz[m * 2048 + d];
            const float uv = u[m * DI_ + d];
            const float du = dl * uv;
            const float r = exp2f(dl * a2[0]);
            float dA = r;
            float yv = 0.f;
#pragma unroll
            for (int n = 0; n < N_; ++n) {
                hs[n] = fmaf(dA, hs[n], du * sB[tt][n]);
                yv = fmaf(hs[n], sC[tt][n], yv);
                dA *= r;
            }
            yv = fmaf(uv, Dpd, yv);
            const float g = yv * silu_f(xz[m * 2048 + DI_ + d]);
            xz[m * 2048 + d] = g;
            gm = fmaxf(gm, fabsf(g));
        }
    } else {
        for (int tt = 0; tt < CL_; ++tt) {
            const size_t m = (size_t)b * T_ + ch * CL_ + tt;
            const float dl = xz[m * 2048 + d];
            const float uv = u[m * DI_ + d];
            const float du = dl * uv;
            float yv = 0.f;
#pragma unroll
            for (int n = 0; n < N_; ++n) {
                const float dA = exp2f(dl * a2[n]);
                hs[n] = fmaf(dA, hs[n], du * sB[tt][n]);
                yv = fmaf(hs[n], sC[tt][n], yv);
            }
            yv = fmaf(uv, Dpd, yv);
            const float g = yv * silu_f(xz[m * 2048 + DI_ + d]);
            xz[m * 2048 + d] = g;
            gm = fmaxf(gm, fabsf(g));
        }
    }
#pragma unroll
    for (int off = 32; off; off >>= 1) gm = fmaxf(gm, __shfl_down(gm, off));
    if ((tid & 63) == 0) atomicMax(gmax, __float_as_uint(gm));
}

extern "C" void kernel_launch(void* const* d_in, const int* in_sizes, int n_in,
                              void* d_out, int out_size, void* d_ws, size_t ws_size,
                              hipStream_t stream) {
    const float* x     = (const float*)d_in[0];
    const float* Wi    = (const float*)d_in[1];
    const float* bi    = (const float*)d_in[2];
    const float* Win   = (const float*)d_in[3];
    const float* convw = (const float*)d_in[4];
    const float* convb = (const float*)d_in[5];
    const float* Wx    = (const float*)d_in[6];
    const float* Wdt   = (const float*)d_in[7];
    const float* bdt   = (const float*)d_in[8];
    const float* A_log = (const float*)d_in[9];
    const float* Dp    = (const float*)d_in[10];
    const float* Wout  = (const float*)d_in[11];
    const float* Wo    = (const float*)d_in[12];
    const float* bo    = (const float*)d_in[13];
    float* out = (float*)d_out;

    // Per-row f32: xz 2048 + u 1024 + dbc 64 + hPS 512 (h | scan P,S) = 3648.
    // h and P/S share the hPS region (disjoint lifetimes, see R12 analysis).
    const size_t rowf = 3648;
    const size_t wextra =
        (3 * 1048576 + 3 * 524288 + 65536 + 3 * 65536 + 3 * 32768) / 2 + 32;
    int CB = BB_;
    while (CB > 1 && ((size_t)CB * T_ * rowf + wextra) * sizeof(float) > ws_size) CB >>= 1;
    const size_t Mc = (size_t)CB * T_;

    const dim3 blk(256);
    const int rowTiles = (int)(Mc / 128);

    float* ws   = (float*)d_ws;
    float* xz   = ws;                    // Mc*2048 (xin/delta/g | z)
    float* u    = xz + Mc * 2048;        // Mc*1024
    float* dbc  = u  + Mc * 1024;        // Mc*64
    float* hPS  = dbc + Mc * 64;         // Mc*512: h (ld 512) / scan P,S
    float* hb   = hPS;
    float* Pbuf = hPS;                               // Mc*128 floats
    float* Sbuf = hPS + (size_t)CB * NCH_ * N_ * DI_;
    unsigned short* WinH  = (unsigned short*)(hPS + Mc * 512);
    unsigned short* WoutH = WinH + 3 * 1048576;
    unsigned short* WoH   = WoutH + 3 * 524288;
    unsigned short* WxH   = WoH + 65536;
    unsigned short* WdtH  = WxH + 3 * 65536;
    unsigned int* scales  = (unsigned int*)(WdtH + 3 * 32768);
    // slots: 0-2 Win, 3-5 Wout, 6 Wo, 7-9 Wx, 10-12 Wdt,
    //        13..16 h[0..3], 17-19 g[l], 20-22 u[l], 23-25 dt[l]

    hipMemsetAsync(scales, 0, 32 * sizeof(unsigned int), stream);

    amax_all<<<dim3(128, 1, 13), blk, 0, stream>>>(Win, Wout, Wx, Wdt, Wo, scales);
    cast_all<<<dim3(64, 1, 13), blk, 0, stream>>>(
        Win, Wout, Wx, Wdt, Wo, WinH, WoutH, WxH, WdtH, WoH, scales);

    for (int c = 0; c < BB_ / CB; ++c) {
        const float* x_c = x + (size_t)c * Mc * DIN_;
        float* out_c     = out + (size_t)c * Mc * DOUT_;

        hipMemsetAsync(scales + 13, 0, 13 * sizeof(unsigned int), stream);

        // h = x @ Wi.T + bi  (fp32, K=64) -> hb (ld 512), amax -> h[0]
        gemm_in<<<dim3(D_ / 128, rowTiles), blk, 0, stream>>>(
            x_c, DIN_, Wi, DIN_, bi, hb, D_, DIN_, scales + 13);

        for (int l = 0; l < L_; ++l) {
            const float* cw_l   = convw + (size_t)l * DI_ * DC_;
            const float* cb_l   = convb + (size_t)l * DI_;
            const float* bdt_l  = bdt  + (size_t)l * DI_;
            const float* Alog_l = A_log + (size_t)l * DI_ * N_;
            const float* Dp_l   = Dp   + (size_t)l * DI_;

            // xz = h @ Win.T  (A fp32 staged-cast, f16 MFMA, pipelined)
            gemm_f32a_t128<0><<<dim3(2048 / 128, rowTiles), blk, 0, stream>>>(
                hb, D_, WinH + (size_t)l * 1048576, D_, nullptr,
                xz, 2048, D_, scales + 13 + l, scales + l, nullptr);

            // u = silu(causal_dwconv(xin) + cb), fused u amax
            conv_silu_kernel<<<dim3(2048), blk, 0, stream>>>(
                xz, cw_l, cb_l, u, Mc * DI_ / 4, scales + 20 + l);

            // dbc = u @ Wx.T  (f16 MFMA 128x64) + dt amax
            gemm_f16u_t64n<<<dim3(1, rowTiles), blk, 0, stream>>>(
                u, DI_, WxH + (size_t)l * 65536, DI_, dbc, 64, DI_,
                scales + 20 + l, scales + 7 + l, scales + 23 + l);

            // delta = softplus(dt @ Wdt.T + bdt) -> xz[:, :1024] (MFMA K=32)
            gemm_delta<<<dim3(DI_ / 128, rowTiles), blk, 0, stream>>>(
                dbc, WdtH + (size_t)l * 32768, bdt_l, xz, 2048,
                scales + 23 + l, scales + 10 + l);

            // chunk-parallel scan; g -> xz[:, :1024], amax -> g[l]
            scan_pass1<<<dim3(CB, DI_ / 256, NCH_), blk, 0, stream>>>(
                xz, u, dbc, Alog_l, Pbuf, Sbuf);
            scan_carry<<<dim3(CB * 64), blk, 0, stream>>>(Pbuf, Sbuf);
            scan_pass3<<<dim3(CB, DI_ / 256, NCH_), blk, 0, stream>>>(
                xz, u, dbc, Alog_l, Dp_l, Sbuf, scales + 17 + l);

            // h = g @ Wout.T  (A fp32 staged-cast) -> hb (P/S dead)
            gemm_f32a_t128<0><<<dim3(D_ / 128, rowTiles), blk, 0, stream>>>(
                xz, 2048, WoutH + (size_t)l * 524288, DI_, nullptr,
                hb, D_, DI_, scales + 17 + l, scales + 3 + l, scales + 14 + l);
        }

        // out = tanh(h @ Wo.T + bo)
        gemm_f32a_t128<3><<<dim3(DOUT_ / 128, rowTiles), blk, 0, stream>>>(
            hb, D_, WoH, D_, bo, out_c, DOUT_, D_,
            scales + 16, scales + 6, nullptr);
    }
}

// Round 14
// 2670.173 us; speedup vs baseline: 1.1474x; 1.0087x over previous
//
#include <hip/hip_runtime.h>
#include <hip/hip_bf16.h>

#define BB_ 16
#define T_ 2048
#define DIN_ 64
#define D_ 512
#define DI_ 1024
#define N_ 16
#define DC_ 4
#define R_ 32
#define L_ 3
#define DOUT_ 128
#define CL_ 64               // scan chunk length (R14: 128->64 for 2x blocks)
#define NCH_ (T_ / CL_)      // 32 chunks

typedef __attribute__((ext_vector_type(8))) _Float16 f16x8;
typedef __attribute__((ext_vector_type(4))) float f32x4;

__device__ __forceinline__ float silu_f(float x) { return x / (1.f + __expf(-x)); }

// fast branch-free softplus: log(1+e^t) = max(t,0) + log(1+e^-|t|)
__device__ __forceinline__ float softplus_f(float t) {
    return fmaxf(t, 0.f) + __logf(1.f + __expf(-fabsf(t)));
}

__device__ __forceinline__ unsigned short f2h(float f) {
    union { _Float16 h; unsigned short u; } c;
    c.h = (_Float16)f;   // RNE
    return c.u;
}

// async global->LDS 16B per lane; LDS dest must be lane-linear (tid*16B).
__device__ __forceinline__ void gload_lds16(const unsigned short* g,
                                            unsigned short* l) {
    __builtin_amdgcn_global_load_lds(
        (const __attribute__((address_space(1))) void*)g,
        (__attribute__((address_space(3))) void*)l, 16, 0, 0);
}

// decode scale from amax bits: s = 2^(11 - e), so s*amax lands in [2^11, 2^12)
__device__ __forceinline__ float decode_scale(unsigned int bits) {
    if (bits == 0u) return 1.f;
    const int E = (int)(bits >> 23) & 0xFF;
    return __uint_as_float((unsigned)(265 - E) << 23);
}

__device__ __forceinline__ uint4 pack8(float4 lo, float4 hi, float s) {
    union { uint4 u; unsigned short h[8]; } r;
    r.h[0] = f2h(lo.x * s); r.h[1] = f2h(lo.y * s);
    r.h[2] = f2h(lo.z * s); r.h[3] = f2h(lo.w * s);
    r.h[4] = f2h(hi.x * s); r.h[5] = f2h(hi.y * s);
    r.h[6] = f2h(hi.z * s); r.h[7] = f2h(hi.w * s);
    return r.u;
}

// regions: 0-2 Win[l] (262144 f4), 3-5 Wout[l] (131072), 6 Wo (16384),
// 7-9 Wx[l] (16384), 10-12 Wdt[l] (8192). slot == region.
__device__ __forceinline__ const float* wregion(
    int r, const float* Win, const float* Wout, const float* Wx,
    const float* Wdt, const float* Wo, size_t* n4)
{
    if (r < 3)       { *n4 = 262144; return Win  + (size_t)r * 1048576; }
    else if (r < 6)  { *n4 = 131072; return Wout + (size_t)(r - 3) * 524288; }
    else if (r == 6) { *n4 = 16384;  return Wo; }
    else if (r < 10) { *n4 = 16384;  return Wx  + (size_t)(r - 7) * 65536; }
    else             { *n4 = 8192;   return Wdt + (size_t)(r - 10) * 32768; }
}

__global__ __launch_bounds__(256) void amax_all(
    const float* __restrict__ Win, const float* __restrict__ Wout,
    const float* __restrict__ Wx, const float* __restrict__ Wdt,
    const float* __restrict__ Wo, unsigned int* __restrict__ scales)
{
    size_t n4;
    const float* p = wregion(blockIdx.z, Win, Wout, Wx, Wdt, Wo, &n4);
    float m = 0.f;
    for (size_t i = (size_t)blockIdx.x * 256 + threadIdx.x; i < n4;
         i += (size_t)gridDim.x * 256) {
        const float4 v = ((const float4*)p)[i];
        m = fmaxf(m, fmaxf(fmaxf(fabsf(v.x), fabsf(v.y)),
                           fmaxf(fabsf(v.z), fabsf(v.w))));
    }
#pragma unroll
    for (int off = 32; off; off >>= 1) m = fmaxf(m, __shfl_down(m, off));
    __shared__ float sm[4];
    if ((threadIdx.x & 63) == 0) sm[threadIdx.x >> 6] = m;
    __syncthreads();
    if (threadIdx.x == 0) {
        const float b = fmaxf(fmaxf(sm[0], sm[1]), fmaxf(sm[2], sm[3]));
        atomicMax(scales + blockIdx.z, __float_as_uint(b));
    }
}

__global__ __launch_bounds__(256) void cast_all(
    const float* __restrict__ Win, const float* __restrict__ Wout,
    const float* __restrict__ Wx, const float* __restrict__ Wdt,
    const float* __restrict__ Wo,
    unsigned short* __restrict__ WinH, unsigned short* __restrict__ WoutH,
    unsigned short* __restrict__ WxH, unsigned short* __restrict__ WdtH,
    unsigned short* __restrict__ WoH,
    const unsigned int* __restrict__ scales)
{
    const int r = blockIdx.z;
    size_t n4;
    const float* p = wregion(r, Win, Wout, Wx, Wdt, Wo, &n4);
    unsigned short* o;
    if (r < 3)       o = WinH  + (size_t)r * 1048576;
    else if (r < 6)  o = WoutH + (size_t)(r - 3) * 524288;
    else if (r == 6) o = WoH;
    else if (r < 10) o = WxH   + (size_t)(r - 7) * 65536;
    else             o = WdtH  + (size_t)(r - 10) * 32768;
    const float s = decode_scale(scales[r]);
    for (size_t i = (size_t)blockIdx.x * 256 + threadIdx.x; i < n4;
         i += (size_t)gridDim.x * 256) {
        const float4 v = ((const float4*)p)[i];
        ((ushort4*)o)[i] = make_ushort4(f2h(v.x * s), f2h(v.y * s),
                                        f2h(v.z * s), f2h(v.w * s));
    }
}

// ------- scaled MFMA GEMM, A fp32 (cast during LDS staging), B f16 --------
// 128x128 tile, BK=32, 4 waves (2x2), per-wave 64x64 = 4x4 frags of 16x16x32.
// A: reg-prefetch pipeline. B: async global_load_lds into double-buffered Bs
// (lane-linear dest), issued during MFMA of the previous tile.
// ACT: 0 = none, 3 = +bias tanh. Output fp32 (+ optional amax).
// NOTE: C must NOT alias A (blocks read A rows outside their C tile).
template<int ACT>
__global__ __launch_bounds__(256) void gemm_f32a_t128(
    const float* __restrict__ A, int lda,
    const unsigned short* __restrict__ B, int ldb,
    const float* __restrict__ bias,
    float* __restrict__ C, int ldc, int K,
    const unsigned int* __restrict__ sa, const unsigned int* __restrict__ sb,
    unsigned int* __restrict__ oamax)
{
    __shared__ __align__(16) unsigned short As[128 * 32];
    __shared__ __align__(16) unsigned short Bs[2][128 * 32];
    const int tid  = threadIdx.x;
    const int lane = tid & 63;
    const int w    = tid >> 6;
    const int wr   = (w >> 1) << 6;
    const int wc   = (w & 1) << 6;
    const int l15  = lane & 15, l4 = lane >> 4;
    const int row0 = blockIdx.y << 7, col0 = blockIdx.x << 7;
    const int tq   = tid >> 2;
    const int tr   = (tid & 3) << 3;

    const float sA  = decode_scale(*sa);
    const float inv = (1.f / sA) * (1.f / decode_scale(*sb));

    const float* Ar0 = A + (size_t)(row0 + tq) * lda + tr;
    const float* Ar1 = A + (size_t)(row0 + 64 + tq) * lda + tr;
    const unsigned short* Br0 = B + (size_t)(col0 + tq) * ldb + tr;
    const unsigned short* Br1 = B + (size_t)(col0 + 64 + tq) * ldb + tr;

    f32x4 acc[4][4];
#pragma unroll
    for (int m = 0; m < 4; ++m)
#pragma unroll
        for (int n = 0; n < 4; ++n) acc[m][n] = (f32x4){0.f, 0.f, 0.f, 0.f};

    float4 a0lo = *(const float4*)(Ar0), a0hi = *(const float4*)(Ar0 + 4);
    float4 a1lo = *(const float4*)(Ar1), a1hi = *(const float4*)(Ar1 + 4);
    // B tile 0 -> Bs[0] (async; drained at first barrier)
    gload_lds16(Br0, &Bs[0][tq * 32 + tr]);
    gload_lds16(Br1, &Bs[0][(64 + tq) * 32 + tr]);

    int cur = 0;
    for (int k0 = 0; k0 < K; k0 += 32) {
        __syncthreads();   // drains B async load for this tile
        *(uint4*)&As[tq * 32 + tr]        = pack8(a0lo, a0hi, sA);
        *(uint4*)&As[(64 + tq) * 32 + tr] = pack8(a1lo, a1hi, sA);
        __syncthreads();

        if (k0 + 32 < K) {
            // issue next B tile into the other buffer (drains at next barrier)
            gload_lds16(Br0 + k0 + 32, &Bs[cur ^ 1][tq * 32 + tr]);
            gload_lds16(Br1 + k0 + 32, &Bs[cur ^ 1][(64 + tq) * 32 + tr]);
            a0lo = *(const float4*)(Ar0 + k0 + 32);
            a0hi = *(const float4*)(Ar0 + k0 + 36);
            a1lo = *(const float4*)(Ar1 + k0 + 32);
            a1hi = *(const float4*)(Ar1 + k0 + 36);
        }

        f16x8 af[4], bfr[4];
#pragma unroll
        for (int m = 0; m < 4; ++m)
            af[m] = *(const f16x8*)&As[(wr + m * 16 + l15) * 32 + l4 * 8];
#pragma unroll
        for (int n = 0; n < 4; ++n)
            bfr[n] = *(const f16x8*)&Bs[cur][(wc + n * 16 + l15) * 32 + l4 * 8];
#pragma unroll
        for (int m = 0; m < 4; ++m)
#pragma unroll
            for (int n = 0; n < 4; ++n)
                acc[m][n] = __builtin_amdgcn_mfma_f32_16x16x32_f16(
                    af[m], bfr[n], acc[m][n], 0, 0, 0);
        cur ^= 1;
    }

    float am = 0.f;
#pragma unroll
    for (int n = 0; n < 4; ++n) {
        const int col = col0 + wc + n * 16 + l15;
        float bc = 0.f;
        if (ACT == 3) bc = bias[col];
#pragma unroll
        for (int m = 0; m < 4; ++m) {
            const int rowb = row0 + wr + m * 16 + (l4 << 2);
#pragma unroll
            for (int r = 0; r < 4; ++r) {
                float v = acc[m][n][r] * inv;
                if (ACT == 3) v = tanhf(v + bc);
                C[(size_t)(rowb + r) * ldc + col] = v;
                am = fmaxf(am, fabsf(v));
            }
        }
    }
    if (oamax) {
#pragma unroll
        for (int off = 32; off; off >>= 1) am = fmaxf(am, __shfl_down(am, off));
        if (lane == 0) atomicMax(oamax, __float_as_uint(am));
    }
}

// ---- dbc GEMM: A fp32 u (staged cast), B f16 Wx. 128x64 tile, pipelined.
// Also emits amax over output cols 0..31 (= dt) for the delta GEMM.
__global__ __launch_bounds__(256) void gemm_f16u_t64n(
    const float* __restrict__ A, int lda,
    const unsigned short* __restrict__ B, int ldb,
    float* __restrict__ C, int ldc, int K,
    const unsigned int* __restrict__ sa, const unsigned int* __restrict__ sb,
    unsigned int* __restrict__ dtmax)
{
    __shared__ __align__(16) unsigned short As[128 * 32];
    __shared__ __align__(16) unsigned short Bs[64 * 32];
    const int tid  = threadIdx.x;
    const int lane = tid & 63;
    const int w    = tid >> 6;
    const int l15  = lane & 15, l4 = lane >> 4;
    const int row0 = blockIdx.y << 7;
    const int tq   = tid >> 2;
    const int tr   = (tid & 3) << 3;

    const float sA  = decode_scale(*sa);
    const float inv = (1.f / sA) * (1.f / decode_scale(*sb));

    const float* Ar0 = A + (size_t)(row0 + tq) * lda + tr;
    const float* Ar1 = A + (size_t)(row0 + 64 + tq) * lda + tr;
    const unsigned short* Br = B + (size_t)tq * ldb + tr;   // 64 rows

    f32x4 acc[2][4];
#pragma unroll
    for (int m = 0; m < 2; ++m)
#pragma unroll
        for (int n = 0; n < 4; ++n) acc[m][n] = (f32x4){0.f, 0.f, 0.f, 0.f};

    float4 a0lo = *(const float4*)(Ar0), a0hi = *(const float4*)(Ar0 + 4);
    float4 a1lo = *(const float4*)(Ar1), a1hi = *(const float4*)(Ar1 + 4);
    uint4  bv   = *(const uint4*)(Br);

    for (int k0 = 0; k0 < K; k0 += 32) {
        __syncthreads();
        *(uint4*)&As[tq * 32 + tr]        = pack8(a0lo, a0hi, sA);
        *(uint4*)&As[(64 + tq) * 32 + tr] = pack8(a1lo, a1hi, sA);
        *(uint4*)&Bs[tq * 32 + tr]        = bv;
        __syncthreads();

        if (k0 + 32 < K) {
            a0lo = *(const float4*)(Ar0 + k0 + 32);
            a0hi = *(const float4*)(Ar0 + k0 + 36);
            a1lo = *(const float4*)(Ar1 + k0 + 32);
            a1hi = *(const float4*)(Ar1 + k0 + 36);
            bv   = *(const uint4*)(Br  + k0 + 32);
        }

        f16x8 af[2], bfr[4];
#pragma unroll
        for (int m = 0; m < 2; ++m)
            af[m] = *(const f16x8*)&As[(w * 32 + m * 16 + l15) * 32 + l4 * 8];
#pragma unroll
        for (int n = 0; n < 4; ++n)
            bfr[n] = *(const f16x8*)&Bs[(n * 16 + l15) * 32 + l4 * 8];
#pragma unroll
        for (int m = 0; m < 2; ++m)
#pragma unroll
            for (int n = 0; n < 4; ++n)
                acc[m][n] = __builtin_amdgcn_mfma_f32_16x16x32_f16(
                    af[m], bfr[n], acc[m][n], 0, 0, 0);
    }

    float am = 0.f;
#pragma unroll
    for (int n = 0; n < 4; ++n) {
        const int col = n * 16 + l15;
#pragma unroll
        for (int m = 0; m < 2; ++m) {
            const int rowb = row0 + w * 32 + m * 16 + (l4 << 2);
#pragma unroll
            for (int r = 0; r < 4; ++r) {
                const float v = acc[m][n][r] * inv;
                C[(size_t)(rowb + r) * ldc + col] = v;
                if (n < 2) am = fmaxf(am, fabsf(v));   // dt cols 0..31
            }
        }
    }
#pragma unroll
    for (int off = 32; off; off >>= 1) am = fmaxf(am, __shfl_down(am, off));
    if (lane == 0) atomicMax(dtmax, __float_as_uint(am));
}

// ---- delta GEMM (K=32, single MFMA step): delta = softplus(dt@Wdt.T + bdt)
// A = dbc fp32 (lda 64, cols 0..31, staged cast), B = Wdt f16 (ldb 32).
// Output fp32 strided (ldc 2048) into the xin slot of xz.
__global__ __launch_bounds__(256) void gemm_delta(
    const float* __restrict__ A,
    const unsigned short* __restrict__ B,
    const float* __restrict__ bias,
    float* __restrict__ C, int ldc,
    const unsigned int* __restrict__ sa, const unsigned int* __restrict__ sb)
{
    __shared__ __align__(16) unsigned short As[128 * 32];
    __shared__ __align__(16) unsigned short Bs[128 * 32];
    const int tid  = threadIdx.x;
    const int lane = tid & 63;
    const int w    = tid >> 6;
    const int wr   = (w >> 1) << 6;
    const int wc   = (w & 1) << 6;
    const int l15  = lane & 15, l4 = lane >> 4;
    const int row0 = blockIdx.y << 7, col0 = blockIdx.x << 7;
    const int tq   = tid >> 2;
    const int tr   = (tid & 3) << 3;

    const float sA  = decode_scale(*sa);
    const float inv = (1.f / sA) * (1.f / decode_scale(*sb));

    const float* Ar0 = A + (size_t)(row0 + tq) * 64 + tr;
    const float* Ar1 = A + (size_t)(row0 + 64 + tq) * 64 + tr;
    const float4 a0lo = *(const float4*)(Ar0), a0hi = *(const float4*)(Ar0 + 4);
    const float4 a1lo = *(const float4*)(Ar1), a1hi = *(const float4*)(Ar1 + 4);
    const uint4 bv0 = *(const uint4*)(B + (size_t)(col0 + tq) * 32 + tr);
    const uint4 bv1 = *(const uint4*)(B + (size_t)(col0 + 64 + tq) * 32 + tr);

    *(uint4*)&As[tq * 32 + tr]        = pack8(a0lo, a0hi, sA);
    *(uint4*)&As[(64 + tq) * 32 + tr] = pack8(a1lo, a1hi, sA);
    *(uint4*)&Bs[tq * 32 + tr]        = bv0;
    *(uint4*)&Bs[(64 + tq) * 32 + tr] = bv1;
    __syncthreads();

    f32x4 acc[4][4];
#pragma unroll
    for (int m = 0; m < 4; ++m)
#pragma unroll
        for (int n = 0; n < 4; ++n) acc[m][n] = (f32x4){0.f, 0.f, 0.f, 0.f};

    f16x8 af[4], bfr[4];
#pragma unroll
    for (int m = 0; m < 4; ++m)
        af[m] = *(const f16x8*)&As[(wr + m * 16 + l15) * 32 + l4 * 8];
#pragma unroll
    for (int n = 0; n < 4; ++n)
        bfr[n] = *(const f16x8*)&Bs[(wc + n * 16 + l15) * 32 + l4 * 8];
#pragma unroll
    for (int m = 0; m < 4; ++m)
#pragma unroll
        for (int n = 0; n < 4; ++n)
            acc[m][n] = __builtin_amdgcn_mfma_f32_16x16x32_f16(
                af[m], bfr[n], acc[m][n], 0, 0, 0);

#pragma unroll
    for (int n = 0; n < 4; ++n) {
        const int col = col0 + wc + n * 16 + l15;
        const float bc = bias[col];
#pragma unroll
        for (int m = 0; m < 4; ++m) {
            const int rowb = row0 + wr + m * 16 + (l4 << 2);
#pragma unroll
            for (int r = 0; r < 4; ++r) {
                const float t = acc[m][n][r] * inv + bc;
                C[(size_t)(rowb + r) * ldc + col] = softplus_f(t);
            }
        }
    }
}

// ---------------- fp32 vector GEMM (input projection, K=64) ----------------
__global__ __launch_bounds__(256) void gemm_in(
    const float* __restrict__ A, int lda,
    const float* __restrict__ B, int ldb,
    const float* __restrict__ bias,
    float* __restrict__ C, int ldc, int K,
    unsigned int* __restrict__ oamax)
{
    __shared__ __align__(16) float As[8][128];
    __shared__ __align__(16) float Bs[8][128];
    const int tid  = threadIdx.x;
    const int row0 = blockIdx.y << 7;
    const int col0 = blockIdx.x << 7;
    const int tx = tid & 15, ty = tid >> 4;

    float acc[8][8];
#pragma unroll
    for (int i = 0; i < 8; ++i)
#pragma unroll
        for (int j = 0; j < 8; ++j) acc[i][j] = 0.f;

    const int arow = tid >> 1;
    const int acol = (tid & 1) << 2;
    const float* Ap = A + (size_t)(row0 + arow) * lda + acol;
    const float* Bp = B + (size_t)(col0 + arow) * ldb + acol;

    for (int k0 = 0; k0 < K; k0 += 8) {
        const float4 av = *(const float4*)(Ap + k0);
        const float4 bv = *(const float4*)(Bp + k0);
        __syncthreads();
        As[acol + 0][arow] = av.x; As[acol + 1][arow] = av.y;
        As[acol + 2][arow] = av.z; As[acol + 3][arow] = av.w;
        Bs[acol + 0][arow] = bv.x; Bs[acol + 1][arow] = bv.y;
        Bs[acol + 2][arow] = bv.z; Bs[acol + 3][arow] = bv.w;
        __syncthreads();
#pragma unroll
        for (int k = 0; k < 8; ++k) {
            float a[8], b[8];
            *(float4*)&a[0] = *(const float4*)&As[k][ty << 3];
            *(float4*)&a[4] = *(const float4*)&As[k][(ty << 3) + 4];
            *(float4*)&b[0] = *(const float4*)&Bs[k][tx << 3];
            *(float4*)&b[4] = *(const float4*)&Bs[k][(tx << 3) + 4];
#pragma unroll
            for (int i = 0; i < 8; ++i)
#pragma unroll
                for (int j = 0; j < 8; ++j)
                    acc[i][j] = fmaf(a[i], b[j], acc[i][j]);
        }
    }

    float bv8[8];
#pragma unroll
    for (int j = 0; j < 8; ++j) bv8[j] = bias[col0 + (tx << 3) + j];

    float am = 0.f;
#pragma unroll
    for (int i = 0; i < 8; ++i) {
        float v[8];
#pragma unroll
        for (int j = 0; j < 8; ++j) {
            v[j] = acc[i][j] + bv8[j];
            am = fmaxf(am, fabsf(v[j]));
        }
        float* Cp = C + (size_t)(row0 + (ty << 3) + i) * ldc + col0 + (tx << 3);
        *(float4*)(Cp)     = make_float4(v[0], v[1], v[2], v[3]);
        *(float4*)(Cp + 4) = make_float4(v[4], v[5], v[6], v[7]);
    }
#pragma unroll
    for (int off = 32; off; off >>= 1) am = fmaxf(am, __shfl_down(am, off));
    if ((tid & 63) == 0) atomicMax(oamax, __float_as_uint(am));
}

// depthwise causal conv (DC=4) + bias + SiLU, float4, grid-stride, fused amax.
__global__ __launch_bounds__(256) void conv_silu_kernel(
    const float* __restrict__ xz, const float* __restrict__ cw,
    const float* __restrict__ cb, float* __restrict__ u,
    size_t total4, unsigned int* __restrict__ uamax)
{
    float am = 0.f;
    for (size_t i = (size_t)blockIdx.x * 256 + threadIdx.x; i < total4;
         i += (size_t)gridDim.x * 256) {
        const size_t e = i * 4;
        const int c = (int)(e & (DI_ - 1));
        const size_t m = e >> 10;
        const int t = (int)(m & (T_ - 1));
        const float* xr = xz + m * 2048 + c;
        const float4 zero = make_float4(0.f, 0.f, 0.f, 0.f);
        const float4 x0 = (t >= 3) ? *(const float4*)(xr - 3 * 2048) : zero;
        const float4 x1 = (t >= 2) ? *(const float4*)(xr - 2 * 2048) : zero;
        const float4 x2 = (t >= 1) ? *(const float4*)(xr - 1 * 2048) : zero;
        const float4 x3 = *(const float4*)(xr);
        const float4 cbv = *(const float4*)(cb + c);
        const float4 w0 = *(const float4*)(cw + (size_t)c * 4);
        const float4 w1 = *(const float4*)(cw + (size_t)(c + 1) * 4);
        const float4 w2 = *(const float4*)(cw + (size_t)(c + 2) * 4);
        const float4 w3 = *(const float4*)(cw + (size_t)(c + 3) * 4);
        float4 r;
        r.x = silu_f(fmaf(x3.x, w0.w, fmaf(x2.x, w0.z, fmaf(x1.x, w0.y, fmaf(x0.x, w0.x, cbv.x)))));
        r.y = silu_f(fmaf(x3.y, w1.w, fmaf(x2.y, w1.z, fmaf(x1.y, w1.y, fmaf(x0.y, w1.x, cbv.y)))));
        r.z = silu_f(fmaf(x3.z, w2.w, fmaf(x2.z, w2.z, fmaf(x1.z, w2.y, fmaf(x0.z, w2.x, cbv.z)))));
        r.w = silu_f(fmaf(x3.w, w3.w, fmaf(x2.w, w3.z, fmaf(x1.w, w3.y, fmaf(x0.w, w3.x, cbv.w)))));
        *(float4*)(u + e) = r;
        am = fmaxf(am, fmaxf(fmaxf(fabsf(r.x), fabsf(r.y)),
                             fmaxf(fabsf(r.z), fabsf(r.w))));
    }
#pragma unroll
    for (int off = 32; off; off >>= 1) am = fmaxf(am, __shfl_down(am, off));
    __shared__ float sm[4];
    if ((threadIdx.x & 63) == 0) sm[threadIdx.x >> 6] = am;
    __syncthreads();
    if (threadIdx.x == 0) {
        const float b = fmaxf(fmaxf(sm[0], sm[1]), fmaxf(sm[2], sm[3]));
        atomicMax(uamax, __float_as_uint(b));
    }
}

// -------- chunk-parallel selective scan (linear recurrence, 3 phases) -----
// Fast path: a2[n] == (n+1)*a2[0] (A_log = log(1..N) tile) -> one exp2/step.

__device__ __forceinline__ bool geo_check(const float* a2) {
    bool ok = true;
#pragma unroll
    for (int n = 1; n < N_; ++n)
        ok = ok && (fabsf(a2[n] - a2[0] * (n + 1)) <=
                    1e-5f * fmaxf(1.f, fabsf(a2[n])));
    return ok;
}

__global__ __launch_bounds__(256) void scan_pass1(
    const float* __restrict__ xz, const float* __restrict__ u,
    const float* __restrict__ dbc, const float* __restrict__ A_log_l,
    float* __restrict__ P, float* __restrict__ S)
{
    __shared__ float sB[CL_][N_];
    const int tid = threadIdx.x;
    const int b = blockIdx.x, ch = blockIdx.z;
    const int d = (blockIdx.y << 8) + tid;

    float a2[N_], Pm[N_], hs[N_];
#pragma unroll
    for (int n = 0; n < N_; ++n) {
        a2[n] = -__expf(A_log_l[d * N_ + n]) * 1.44269504f;
        Pm[n] = 1.f; hs[n] = 0.f;
    }
    const bool geo = geo_check(a2);
    for (int i = tid; i < CL_ * N_; i += 256) {
        const int tl = i >> 4, n = i & 15;
        sB[tl][n] = dbc[((size_t)b * T_ + ch * CL_ + tl) * 64 + 32 + n];
    }
    __syncthreads();

    if (geo) {
        for (int tt = 0; tt < CL_; ++tt) {
            const size_t m = (size_t)b * T_ + ch * CL_ + tt;
            const float dl = xz[m * 2048 + d];
            const float du = dl * u[m * DI_ + d];
            const float r = exp2f(dl * a2[0]);
            float dA = r;
#pragma unroll
            for (int n = 0; n < N_; ++n) {
                Pm[n] *= dA;
                hs[n] = fmaf(dA, hs[n], du * sB[tt][n]);
                dA *= r;
            }
        }
    } else {
        for (int tt = 0; tt < CL_; ++tt) {
            const size_t m = (size_t)b * T_ + ch * CL_ + tt;
            const float dl = xz[m * 2048 + d];
            const float du = dl * u[m * DI_ + d];
#pragma unroll
            for (int n = 0; n < N_; ++n) {
                const float dA = exp2f(dl * a2[n]);
                Pm[n] *= dA;
                hs[n] = fmaf(dA, hs[n], du * sB[tt][n]);
            }
        }
    }
#pragma unroll
    for (int n = 0; n < N_; ++n) {
        const size_t idx = (size_t)(((b * NCH_ + ch) * N_ + n) << 10) + d;
        P[idx] = Pm[n]; S[idx] = hs[n];
    }
}

__global__ __launch_bounds__(256) void scan_carry(
    const float* __restrict__ P, float* __restrict__ S)
{
    const size_t gid = (size_t)blockIdx.x * 256 + threadIdx.x;
    const int d = (int)(gid & 1023);
    const int n = (int)((gid >> 10) & 15);
    const int b = (int)(gid >> 14);
    float hc = 0.f;
    for (int ch = 0; ch < NCH_; ++ch) {
        const size_t idx = (size_t)(((b * NCH_ + ch) * N_ + n) << 10) + d;
        const float p = P[idx], s = S[idx];
        S[idx] = hc;
        hc = fmaf(p, hc, s);
    }
}

__global__ __launch_bounds__(256) void scan_pass3(
    float* __restrict__ xz, const float* __restrict__ u,
    const float* __restrict__ dbc, const float* __restrict__ A_log_l,
    const float* __restrict__ Dp_l, const float* __restrict__ S,
    unsigned int* __restrict__ gmax)
{
    __shared__ float sB[CL_][N_];
    __shared__ float sC[CL_][N_];
    const int tid = threadIdx.x;
    const int b = blockIdx.x, ch = blockIdx.z;
    const int d = (blockIdx.y << 8) + tid;

    float a2[N_], hs[N_];
#pragma unroll
    for (int n = 0; n < N_; ++n) {
        a2[n] = -__expf(A_log_l[d * N_ + n]) * 1.44269504f;
        hs[n] = S[(size_t)(((b * NCH_ + ch) * N_ + n) << 10) + d];
    }
    const bool geo = geo_check(a2);
    const float Dpd = Dp_l[d];
    for (int i = tid; i < CL_ * N_; i += 256) {
        const int tl = i >> 4, n = i & 15;
        const size_t base = ((size_t)b * T_ + ch * CL_ + tl) * 64;
        sB[tl][n] = dbc[base + 32 + n];
        sC[tl][n] = dbc[base + 48 + n];
    }
    __syncthreads();

    float gm = 0.f;
    if (geo) {
        for (int tt = 0; tt < CL_; ++tt) {
            const size_t m = (size_t)b * T_ + ch * CL_ + tt;
            const float dl = xz[m * 2048 + d];
            const float uv = u[m * DI_ + d];
            const float du = dl * uv;
            const float r = exp2f(dl * a2[0]);
            float dA = r;
            float yv = 0.f;
#pragma unroll
            for (int n = 0; n < N_; ++n) {
                hs[n] = fmaf(dA, hs[n], du * sB[tt][n]);
                yv = fmaf(hs[n], sC[tt][n], yv);
                dA *= r;
            }
            yv = fmaf(uv, Dpd, yv);
            const float g = yv * silu_f(xz[m * 2048 + DI_ + d]);
            xz[m * 2048 + d] = g;
            gm = fmaxf(gm, fabsf(g));
        }
    } else {
        for (int tt = 0; tt < CL_; ++tt) {
            const size_t m = (size_t)b * T_ + ch * CL_ + tt;
            const float dl = xz[m * 2048 + d];
            const float uv = u[m * DI_ + d];
            const float du = dl * uv;
            float yv = 0.f;
#pragma unroll
            for (int n = 0; n < N_; ++n) {
                const float dA = exp2f(dl * a2[n]);
                hs[n] = fmaf(dA, hs[n], du * sB[tt][n]);
                yv = fmaf(hs[n], sC[tt][n], yv);
            }
            yv = fmaf(uv, Dpd, yv);
            const float g = yv * silu_f(xz[m * 2048 + DI_ + d]);
            xz[m * 2048 + d] = g;
            gm = fmaxf(gm, fabsf(g));
        }
    }
#pragma unroll
    for (int off = 32; off; off >>= 1) gm = fmaxf(gm, __shfl_down(gm, off));
    if ((tid & 63) == 0) atomicMax(gmax, __float_as_uint(gm));
}

extern "C" void kernel_launch(void* const* d_in, const int* in_sizes, int n_in,
                              void* d_out, int out_size, void* d_ws, size_t ws_size,
                              hipStream_t stream) {
    const float* x     = (const float*)d_in[0];
    const float* Wi    = (const float*)d_in[1];
    const float* bi    = (const float*)d_in[2];
    const float* Win   = (const float*)d_in[3];
    const float* convw = (const float*)d_in[4];
    const float* convb = (const float*)d_in[5];
    const float* Wx    = (const float*)d_in[6];
    const float* Wdt   = (const float*)d_in[7];
    const float* bdt   = (const float*)d_in[8];
    const float* A_log = (const float*)d_in[9];
    const float* Dp    = (const float*)d_in[10];
    const float* Wout  = (const float*)d_in[11];
    const float* Wo    = (const float*)d_in[12];
    const float* bo    = (const float*)d_in[13];
    float* out = (float*)d_out;

    // Per-row f32: xz 2048 + u 1024 + dbc 64 + hPS 512 (h | scan P,S) = 3648.
    // h and P/S share the hPS region (disjoint lifetimes).
    const size_t rowf = 3648;
    const size_t wextra =
        (3 * 1048576 + 3 * 524288 + 65536 + 3 * 65536 + 3 * 32768) / 2 + 32;
    int CB = BB_;
    while (CB > 1 && ((size_t)CB * T_ * rowf + wextra) * sizeof(float) > ws_size) CB >>= 1;
    const size_t Mc = (size_t)CB * T_;

    const dim3 blk(256);
    const int rowTiles = (int)(Mc / 128);

    float* ws   = (float*)d_ws;
    float* xz   = ws;                    // Mc*2048 (xin/delta/g | z)
    float* u    = xz + Mc * 2048;        // Mc*1024
    float* dbc  = u  + Mc * 1024;        // Mc*64
    float* hPS  = dbc + Mc * 64;         // Mc*512: h (ld 512) / scan P,S
    float* hb   = hPS;
    float* Pbuf = hPS;                               // CB*NCH*N*DI floats
    float* Sbuf = hPS + (size_t)CB * NCH_ * N_ * DI_;
    unsigned short* WinH  = (unsigned short*)(hPS + Mc * 512);
    unsigned short* WoutH = WinH + 3 * 1048576;
    unsigned short* WoH   = WoutH + 3 * 524288;
    unsigned short* WxH   = WoH + 65536;
    unsigned short* WdtH  = WxH + 3 * 65536;
    unsigned int* scales  = (unsigned int*)(WdtH + 3 * 32768);
    // slots: 0-2 Win, 3-5 Wout, 6 Wo, 7-9 Wx, 10-12 Wdt,
    //        13..16 h[0..3], 17-19 g[l], 20-22 u[l], 23-25 dt[l]

    hipMemsetAsync(scales, 0, 32 * sizeof(unsigned int), stream);

    amax_all<<<dim3(128, 1, 13), blk, 0, stream>>>(Win, Wout, Wx, Wdt, Wo, scales);
    cast_all<<<dim3(64, 1, 13), blk, 0, stream>>>(
        Win, Wout, Wx, Wdt, Wo, WinH, WoutH, WxH, WdtH, WoH, scales);

    for (int c = 0; c < BB_ / CB; ++c) {
        const float* x_c = x + (size_t)c * Mc * DIN_;
        float* out_c     = out + (size_t)c * Mc * DOUT_;

        hipMemsetAsync(scales + 13, 0, 13 * sizeof(unsigned int), stream);

        // h = x @ Wi.T + bi  (fp32, K=64) -> hb (ld 512), amax -> h[0]
        gemm_in<<<dim3(D_ / 128, rowTiles), blk, 0, stream>>>(
            x_c, DIN_, Wi, DIN_, bi, hb, D_, DIN_, scales + 13);

        for (int l = 0; l < L_; ++l) {
            const float* cw_l   = convw + (size_t)l * DI_ * DC_;
            const float* cb_l   = convb + (size_t)l * DI_;
            const float* bdt_l  = bdt  + (size_t)l * DI_;
            const float* Alog_l = A_log + (size_t)l * DI_ * N_;
            const float* Dp_l   = Dp   + (size_t)l * DI_;

            // xz = h @ Win.T  (A fp32 staged-cast, B async-lds, pipelined)
            gemm_f32a_t128<0><<<dim3(2048 / 128, rowTiles), blk, 0, stream>>>(
                hb, D_, WinH + (size_t)l * 1048576, D_, nullptr,
                xz, 2048, D_, scales + 13 + l, scales + l, nullptr);

            // u = silu(causal_dwconv(xin) + cb), fused u amax
            conv_silu_kernel<<<dim3(2048), blk, 0, stream>>>(
                xz, cw_l, cb_l, u, Mc * DI_ / 4, scales + 20 + l);

            // dbc = u @ Wx.T  (f16 MFMA 128x64) + dt amax
            gemm_f16u_t64n<<<dim3(1, rowTiles), blk, 0, stream>>>(
                u, DI_, WxH + (size_t)l * 65536, DI_, dbc, 64, DI_,
                scales + 20 + l, scales + 7 + l, scales + 23 + l);

            // delta = softplus(dt @ Wdt.T + bdt) -> xz[:, :1024] (MFMA K=32)
            gemm_delta<<<dim3(DI_ / 128, rowTiles), blk, 0, stream>>>(
                dbc, WdtH + (size_t)l * 32768, bdt_l, xz, 2048,
                scales + 23 + l, scales + 10 + l);

            // chunk-parallel scan; g -> xz[:, :1024], amax -> g[l]
            scan_pass1<<<dim3(CB, DI_ / 256, NCH_), blk, 0, stream>>>(
                xz, u, dbc, Alog_l, Pbuf, Sbuf);
            scan_carry<<<dim3(CB * 64), blk, 0, stream>>>(Pbuf, Sbuf);
            scan_pass3<<<dim3(CB, DI_ / 256, NCH_), blk, 0, stream>>>(
                xz, u, dbc, Alog_l, Dp_l, Sbuf, scales + 17 + l);

            // h = g @ Wout.T  (A fp32 staged-cast) -> hb (P/S dead)
            gemm_f32a_t128<0><<<dim3(D_ / 128, rowTiles), blk, 0, stream>>>(
                xz, 2048, WoutH + (size_t)l * 524288, DI_, nullptr,
                hb, D_, DI_, scales + 17 + l, scales + 3 + l, scales + 14 + l);
        }

        // out = tanh(h @ Wo.T + bo)
        gemm_f32a_t128<3><<<dim3(DOUT_ / 128, rowTiles), blk, 0, stream>>>(
            hb, D_, WoH, D_, bo, out_c, DOUT_, D_,
            scales + 16, scales + 6, nullptr);
    }
}

// Round 15
// 2593.921 us; speedup vs baseline: 1.1812x; 1.0294x over previous
//
#include <hip/hip_runtime.h>
#include <hip/hip_bf16.h>

#define BB_ 16
#define T_ 2048
#define DIN_ 64
#define D_ 512
#define DI_ 1024
#define N_ 16
#define DC_ 4
#define R_ 32
#define L_ 3
#define DOUT_ 128
#define CL_ 64               // scan chunk length
#define NCH_ (T_ / CL_)      // 32 chunks

typedef __attribute__((ext_vector_type(8))) _Float16 f16x8;
typedef __attribute__((ext_vector_type(4))) float f32x4;

__device__ __forceinline__ float silu_f(float x) { return x / (1.f + __expf(-x)); }

// fast branch-free softplus: log(1+e^t) = max(t,0) + log(1+e^-|t|)
__device__ __forceinline__ float softplus_f(float t) {
    return fmaxf(t, 0.f) + __logf(1.f + __expf(-fabsf(t)));
}

__device__ __forceinline__ unsigned short f2h(float f) {
    union { _Float16 h; unsigned short u; } c;
    c.h = (_Float16)f;   // RNE
    return c.u;
}

// async global->LDS 16B per lane; LDS dest must be lane-linear (tid*16B).
__device__ __forceinline__ void gload_lds16(const unsigned short* g,
                                            unsigned short* l) {
    __builtin_amdgcn_global_load_lds(
        (const __attribute__((address_space(1))) void*)g,
        (__attribute__((address_space(3))) void*)l, 16, 0, 0);
}

// decode scale from amax bits: s = 2^(11 - e), so s*amax lands in [2^11, 2^12)
__device__ __forceinline__ float decode_scale(unsigned int bits) {
    if (bits == 0u) return 1.f;
    const int E = (int)(bits >> 23) & 0xFF;
    return __uint_as_float((unsigned)(265 - E) << 23);
}

__device__ __forceinline__ uint4 pack8(float4 lo, float4 hi, float s) {
    union { uint4 u; unsigned short h[8]; } r;
    r.h[0] = f2h(lo.x * s); r.h[1] = f2h(lo.y * s);
    r.h[2] = f2h(lo.z * s); r.h[3] = f2h(lo.w * s);
    r.h[4] = f2h(hi.x * s); r.h[5] = f2h(hi.y * s);
    r.h[6] = f2h(hi.z * s); r.h[7] = f2h(hi.w * s);
    return r.u;
}

// regions: 0-2 Win[l] (262144 f4), 3-5 Wout[l] (131072), 6 Wo (16384),
// 7-9 Wx[l] (16384). slot == region.
__device__ __forceinline__ const float* wregion(
    int r, const float* Win, const float* Wout, const float* Wx,
    const float* Wo, size_t* n4)
{
    if (r < 3)       { *n4 = 262144; return Win  + (size_t)r * 1048576; }
    else if (r < 6)  { *n4 = 131072; return Wout + (size_t)(r - 3) * 524288; }
    else if (r == 6) { *n4 = 16384;  return Wo; }
    else             { *n4 = 16384;  return Wx  + (size_t)(r - 7) * 65536; }
}

__global__ __launch_bounds__(256) void amax_all(
    const float* __restrict__ Win, const float* __restrict__ Wout,
    const float* __restrict__ Wx, const float* __restrict__ Wo,
    unsigned int* __restrict__ scales)
{
    size_t n4;
    const float* p = wregion(blockIdx.z, Win, Wout, Wx, Wo, &n4);
    float m = 0.f;
    for (size_t i = (size_t)blockIdx.x * 256 + threadIdx.x; i < n4;
         i += (size_t)gridDim.x * 256) {
        const float4 v = ((const float4*)p)[i];
        m = fmaxf(m, fmaxf(fmaxf(fabsf(v.x), fabsf(v.y)),
                           fmaxf(fabsf(v.z), fabsf(v.w))));
    }
#pragma unroll
    for (int off = 32; off; off >>= 1) m = fmaxf(m, __shfl_down(m, off));
    __shared__ float sm[4];
    if ((threadIdx.x & 63) == 0) sm[threadIdx.x >> 6] = m;
    __syncthreads();
    if (threadIdx.x == 0) {
        const float b = fmaxf(fmaxf(sm[0], sm[1]), fmaxf(sm[2], sm[3]));
        atomicMax(scales + blockIdx.z, __float_as_uint(b));
    }
}

__global__ __launch_bounds__(256) void cast_all(
    const float* __restrict__ Win, const float* __restrict__ Wout,
    const float* __restrict__ Wx, const float* __restrict__ Wo,
    unsigned short* __restrict__ WinH, unsigned short* __restrict__ WoutH,
    unsigned short* __restrict__ WxH, unsigned short* __restrict__ WoH,
    const unsigned int* __restrict__ scales)
{
    const int r = blockIdx.z;
    size_t n4;
    const float* p = wregion(r, Win, Wout, Wx, Wo, &n4);
    unsigned short* o;
    if (r < 3)       o = WinH  + (size_t)r * 1048576;
    else if (r < 6)  o = WoutH + (size_t)(r - 3) * 524288;
    else if (r == 6) o = WoH;
    else             o = WxH   + (size_t)(r - 7) * 65536;
    const float s = decode_scale(scales[r]);
    for (size_t i = (size_t)blockIdx.x * 256 + threadIdx.x; i < n4;
         i += (size_t)gridDim.x * 256) {
        const float4 v = ((const float4*)p)[i];
        ((ushort4*)o)[i] = make_ushort4(f2h(v.x * s), f2h(v.y * s),
                                        f2h(v.z * s), f2h(v.w * s));
    }
}

// ------- scaled MFMA GEMM, A fp32 (cast during LDS staging), B f16 --------
// 128x128 tile, BK=32, 4 waves (2x2), per-wave 64x64 = 4x4 frags of 16x16x32.
// A: reg-prefetch pipeline. B: async global_load_lds, double-buffered.
// ACT: 0 = none, 3 = +bias tanh. Output fp32 (+ optional amax).
// NOTE: C must NOT alias A.
template<int ACT>
__global__ __launch_bounds__(256) void gemm_f32a_t128(
    const float* __restrict__ A, int lda,
    const unsigned short* __restrict__ B, int ldb,
    const float* __restrict__ bias,
    float* __restrict__ C, int ldc, int K,
    const unsigned int* __restrict__ sa, const unsigned int* __restrict__ sb,
    unsigned int* __restrict__ oamax)
{
    __shared__ __align__(16) unsigned short As[128 * 32];
    __shared__ __align__(16) unsigned short Bs[2][128 * 32];
    const int tid  = threadIdx.x;
    const int lane = tid & 63;
    const int w    = tid >> 6;
    const int wr   = (w >> 1) << 6;
    const int wc   = (w & 1) << 6;
    const int l15  = lane & 15, l4 = lane >> 4;
    const int row0 = blockIdx.y << 7, col0 = blockIdx.x << 7;
    const int tq   = tid >> 2;
    const int tr   = (tid & 3) << 3;

    const float sA  = decode_scale(*sa);
    const float inv = (1.f / sA) * (1.f / decode_scale(*sb));

    const float* Ar0 = A + (size_t)(row0 + tq) * lda + tr;
    const float* Ar1 = A + (size_t)(row0 + 64 + tq) * lda + tr;
    const unsigned short* Br0 = B + (size_t)(col0 + tq) * ldb + tr;
    const unsigned short* Br1 = B + (size_t)(col0 + 64 + tq) * ldb + tr;

    f32x4 acc[4][4];
#pragma unroll
    for (int m = 0; m < 4; ++m)
#pragma unroll
        for (int n = 0; n < 4; ++n) acc[m][n] = (f32x4){0.f, 0.f, 0.f, 0.f};

    float4 a0lo = *(const float4*)(Ar0), a0hi = *(const float4*)(Ar0 + 4);
    float4 a1lo = *(const float4*)(Ar1), a1hi = *(const float4*)(Ar1 + 4);
    gload_lds16(Br0, &Bs[0][tq * 32 + tr]);
    gload_lds16(Br1, &Bs[0][(64 + tq) * 32 + tr]);

    int cur = 0;
    for (int k0 = 0; k0 < K; k0 += 32) {
        __syncthreads();
        *(uint4*)&As[tq * 32 + tr]        = pack8(a0lo, a0hi, sA);
        *(uint4*)&As[(64 + tq) * 32 + tr] = pack8(a1lo, a1hi, sA);
        __syncthreads();

        if (k0 + 32 < K) {
            gload_lds16(Br0 + k0 + 32, &Bs[cur ^ 1][tq * 32 + tr]);
            gload_lds16(Br1 + k0 + 32, &Bs[cur ^ 1][(64 + tq) * 32 + tr]);
            a0lo = *(const float4*)(Ar0 + k0 + 32);
            a0hi = *(const float4*)(Ar0 + k0 + 36);
            a1lo = *(const float4*)(Ar1 + k0 + 32);
            a1hi = *(const float4*)(Ar1 + k0 + 36);
        }

        f16x8 af[4], bfr[4];
#pragma unroll
        for (int m = 0; m < 4; ++m)
            af[m] = *(const f16x8*)&As[(wr + m * 16 + l15) * 32 + l4 * 8];
#pragma unroll
        for (int n = 0; n < 4; ++n)
            bfr[n] = *(const f16x8*)&Bs[cur][(wc + n * 16 + l15) * 32 + l4 * 8];
#pragma unroll
        for (int m = 0; m < 4; ++m)
#pragma unroll
            for (int n = 0; n < 4; ++n)
                acc[m][n] = __builtin_amdgcn_mfma_f32_16x16x32_f16(
                    af[m], bfr[n], acc[m][n], 0, 0, 0);
        cur ^= 1;
    }

    float am = 0.f;
#pragma unroll
    for (int n = 0; n < 4; ++n) {
        const int col = col0 + wc + n * 16 + l15;
        float bc = 0.f;
        if (ACT == 3) bc = bias[col];
#pragma unroll
        for (int m = 0; m < 4; ++m) {
            const int rowb = row0 + wr + m * 16 + (l4 << 2);
#pragma unroll
            for (int r = 0; r < 4; ++r) {
                float v = acc[m][n][r] * inv;
                if (ACT == 3) v = tanhf(v + bc);
                C[(size_t)(rowb + r) * ldc + col] = v;
                am = fmaxf(am, fabsf(v));
            }
        }
    }
    if (oamax) {
#pragma unroll
        for (int off = 32; off; off >>= 1) am = fmaxf(am, __shfl_down(am, off));
        if (lane == 0) atomicMax(oamax, __float_as_uint(am));
    }
}

// ---- dbc GEMM: A fp32 u (staged cast), B f16 Wx. 128x64 tile, pipelined.
__global__ __launch_bounds__(256) void gemm_f16u_t64n(
    const float* __restrict__ A, int lda,
    const unsigned short* __restrict__ B, int ldb,
    float* __restrict__ C, int ldc, int K,
    const unsigned int* __restrict__ sa, const unsigned int* __restrict__ sb)
{
    __shared__ __align__(16) unsigned short As[128 * 32];
    __shared__ __align__(16) unsigned short Bs[64 * 32];
    const int tid  = threadIdx.x;
    const int lane = tid & 63;
    const int w    = tid >> 6;
    const int l15  = lane & 15, l4 = lane >> 4;
    const int row0 = blockIdx.y << 7;
    const int tq   = tid >> 2;
    const int tr   = (tid & 3) << 3;

    const float sA  = decode_scale(*sa);
    const float inv = (1.f / sA) * (1.f / decode_scale(*sb));

    const float* Ar0 = A + (size_t)(row0 + tq) * lda + tr;
    const float* Ar1 = A + (size_t)(row0 + 64 + tq) * lda + tr;
    const unsigned short* Br = B + (size_t)tq * ldb + tr;   // 64 rows

    f32x4 acc[2][4];
#pragma unroll
    for (int m = 0; m < 2; ++m)
#pragma unroll
        for (int n = 0; n < 4; ++n) acc[m][n] = (f32x4){0.f, 0.f, 0.f, 0.f};

    float4 a0lo = *(const float4*)(Ar0), a0hi = *(const float4*)(Ar0 + 4);
    float4 a1lo = *(const float4*)(Ar1), a1hi = *(const float4*)(Ar1 + 4);
    uint4  bv   = *(const uint4*)(Br);

    for (int k0 = 0; k0 < K; k0 += 32) {
        __syncthreads();
        *(uint4*)&As[tq * 32 + tr]        = pack8(a0lo, a0hi, sA);
        *(uint4*)&As[(64 + tq) * 32 + tr] = pack8(a1lo, a1hi, sA);
        *(uint4*)&Bs[tq * 32 + tr]        = bv;
        __syncthreads();

        if (k0 + 32 < K) {
            a0lo = *(const float4*)(Ar0 + k0 + 32);
            a0hi = *(const float4*)(Ar0 + k0 + 36);
            a1lo = *(const float4*)(Ar1 + k0 + 32);
            a1hi = *(const float4*)(Ar1 + k0 + 36);
            bv   = *(const uint4*)(Br  + k0 + 32);
        }

        f16x8 af[2], bfr[4];
#pragma unroll
        for (int m = 0; m < 2; ++m)
            af[m] = *(const f16x8*)&As[(w * 32 + m * 16 + l15) * 32 + l4 * 8];
#pragma unroll
        for (int n = 0; n < 4; ++n)
            bfr[n] = *(const f16x8*)&Bs[(n * 16 + l15) * 32 + l4 * 8];
#pragma unroll
        for (int m = 0; m < 2; ++m)
#pragma unroll
            for (int n = 0; n < 4; ++n)
                acc[m][n] = __builtin_amdgcn_mfma_f32_16x16x32_f16(
                    af[m], bfr[n], acc[m][n], 0, 0, 0);
    }

#pragma unroll
    for (int n = 0; n < 4; ++n) {
        const int col = n * 16 + l15;
#pragma unroll
        for (int m = 0; m < 2; ++m) {
            const int rowb = row0 + w * 32 + m * 16 + (l4 << 2);
#pragma unroll
            for (int r = 0; r < 4; ++r)
                C[(size_t)(rowb + r) * ldc + col] = acc[m][n][r] * inv;
        }
    }
}

// ---------------- fp32 vector GEMM (input projection, K=64) ----------------
__global__ __launch_bounds__(256) void gemm_in(
    const float* __restrict__ A, int lda,
    const float* __restrict__ B, int ldb,
    const float* __restrict__ bias,
    float* __restrict__ C, int ldc, int K,
    unsigned int* __restrict__ oamax)
{
    __shared__ __align__(16) float As[8][128];
    __shared__ __align__(16) float Bs[8][128];
    const int tid  = threadIdx.x;
    const int row0 = blockIdx.y << 7;
    const int col0 = blockIdx.x << 7;
    const int tx = tid & 15, ty = tid >> 4;

    float acc[8][8];
#pragma unroll
    for (int i = 0; i < 8; ++i)
#pragma unroll
        for (int j = 0; j < 8; ++j) acc[i][j] = 0.f;

    const int arow = tid >> 1;
    const int acol = (tid & 1) << 2;
    const float* Ap = A + (size_t)(row0 + arow) * lda + acol;
    const float* Bp = B + (size_t)(col0 + arow) * ldb + acol;

    for (int k0 = 0; k0 < K; k0 += 8) {
        const float4 av = *(const float4*)(Ap + k0);
        const float4 bv = *(const float4*)(Bp + k0);
        __syncthreads();
        As[acol + 0][arow] = av.x; As[acol + 1][arow] = av.y;
        As[acol + 2][arow] = av.z; As[acol + 3][arow] = av.w;
        Bs[acol + 0][arow] = bv.x; Bs[acol + 1][arow] = bv.y;
        Bs[acol + 2][arow] = bv.z; Bs[acol + 3][arow] = bv.w;
        __syncthreads();
#pragma unroll
        for (int k = 0; k < 8; ++k) {
            float a[8], b[8];
            *(float4*)&a[0] = *(const float4*)&As[k][ty << 3];
            *(float4*)&a[4] = *(const float4*)&As[k][(ty << 3) + 4];
            *(float4*)&b[0] = *(const float4*)&Bs[k][tx << 3];
            *(float4*)&b[4] = *(const float4*)&Bs[k][(tx << 3) + 4];
#pragma unroll
            for (int i = 0; i < 8; ++i)
#pragma unroll
                for (int j = 0; j < 8; ++j)
                    acc[i][j] = fmaf(a[i], b[j], acc[i][j]);
        }
    }

    float bv8[8];
#pragma unroll
    for (int j = 0; j < 8; ++j) bv8[j] = bias[col0 + (tx << 3) + j];

    float am = 0.f;
#pragma unroll
    for (int i = 0; i < 8; ++i) {
        float v[8];
#pragma unroll
        for (int j = 0; j < 8; ++j) {
            v[j] = acc[i][j] + bv8[j];
            am = fmaxf(am, fabsf(v[j]));
        }
        float* Cp = C + (size_t)(row0 + (ty << 3) + i) * ldc + col0 + (tx << 3);
        *(float4*)(Cp)     = make_float4(v[0], v[1], v[2], v[3]);
        *(float4*)(Cp + 4) = make_float4(v[4], v[5], v[6], v[7]);
    }
#pragma unroll
    for (int off = 32; off; off >>= 1) am = fmaxf(am, __shfl_down(am, off));
    if ((tid & 63) == 0) atomicMax(oamax, __float_as_uint(am));
}

// depthwise causal conv (DC=4) + bias + SiLU, float4, grid-stride, fused amax.
__global__ __launch_bounds__(256) void conv_silu_kernel(
    const float* __restrict__ xz, const float* __restrict__ cw,
    const float* __restrict__ cb, float* __restrict__ u,
    size_t total4, unsigned int* __restrict__ uamax)
{
    float am = 0.f;
    for (size_t i = (size_t)blockIdx.x * 256 + threadIdx.x; i < total4;
         i += (size_t)gridDim.x * 256) {
        const size_t e = i * 4;
        const int c = (int)(e & (DI_ - 1));
        const size_t m = e >> 10;
        const int t = (int)(m & (T_ - 1));
        const float* xr = xz + m * 2048 + c;
        const float4 zero = make_float4(0.f, 0.f, 0.f, 0.f);
        const float4 x0 = (t >= 3) ? *(const float4*)(xr - 3 * 2048) : zero;
        const float4 x1 = (t >= 2) ? *(const float4*)(xr - 2 * 2048) : zero;
        const float4 x2 = (t >= 1) ? *(const float4*)(xr - 1 * 2048) : zero;
        const float4 x3 = *(const float4*)(xr);
        const float4 cbv = *(const float4*)(cb + c);
        const float4 w0 = *(const float4*)(cw + (size_t)c * 4);
        const float4 w1 = *(const float4*)(cw + (size_t)(c + 1) * 4);
        const float4 w2 = *(const float4*)(cw + (size_t)(c + 2) * 4);
        const float4 w3 = *(const float4*)(cw + (size_t)(c + 3) * 4);
        float4 r;
        r.x = silu_f(fmaf(x3.x, w0.w, fmaf(x2.x, w0.z, fmaf(x1.x, w0.y, fmaf(x0.x, w0.x, cbv.x)))));
        r.y = silu_f(fmaf(x3.y, w1.w, fmaf(x2.y, w1.z, fmaf(x1.y, w1.y, fmaf(x0.y, w1.x, cbv.y)))));
        r.z = silu_f(fmaf(x3.z, w2.w, fmaf(x2.z, w2.z, fmaf(x1.z, w2.y, fmaf(x0.z, w2.x, cbv.z)))));
        r.w = silu_f(fmaf(x3.w, w3.w, fmaf(x2.w, w3.z, fmaf(x1.w, w3.y, fmaf(x0.w, w3.x, cbv.w)))));
        *(float4*)(u + e) = r;
        am = fmaxf(am, fmaxf(fmaxf(fabsf(r.x), fabsf(r.y)),
                             fmaxf(fabsf(r.z), fabsf(r.w))));
    }
#pragma unroll
    for (int off = 32; off; off >>= 1) am = fmaxf(am, __shfl_down(am, off));
    __shared__ float sm[4];
    if ((threadIdx.x & 63) == 0) sm[threadIdx.x >> 6] = am;
    __syncthreads();
    if (threadIdx.x == 0) {
        const float b = fmaxf(fmaxf(sm[0], sm[1]), fmaxf(sm[2], sm[3]));
        atomicMax(uamax, __float_as_uint(b));
    }
}

// -------- chunk-parallel selective scan, delta fused (3 phases) -----------
// delta computed inline: dl = softplus(dot32(dbc[m,0:32], Wdt[d,:]) + bdt[d]).
// dbc rows (all 64 cols: dt|B|C) staged in LDS; dt reads are LDS broadcasts.
// Fast path: a2[n] == (n+1)*a2[0] -> one exp2/step. P via exp2(a2[n]*sum(dl)).

__device__ __forceinline__ bool geo_check(const float* a2) {
    bool ok = true;
#pragma unroll
    for (int n = 1; n < N_; ++n)
        ok = ok && (fabsf(a2[n] - a2[0] * (n + 1)) <=
                    1e-5f * fmaxf(1.f, fabsf(a2[n])));
    return ok;
}

__global__ __launch_bounds__(256) void scan_pass1(
    const float* __restrict__ u, const float* __restrict__ dbc,
    const float* __restrict__ A_log_l, const float* __restrict__ Wdt_l,
    const float* __restrict__ bdt_l,
    float* __restrict__ P, float* __restrict__ S)
{
    __shared__ __align__(16) float sAll[CL_][64];
    const int tid = threadIdx.x;
    const int b = blockIdx.x, ch = blockIdx.z;
    const int d = (blockIdx.y << 8) + tid;

    float a2[N_], hs[N_];
#pragma unroll
    for (int n = 0; n < N_; ++n) {
        a2[n] = -__expf(A_log_l[d * N_ + n]) * 1.44269504f;
        hs[n] = 0.f;
    }
    const bool geo = geo_check(a2);
    float wdt[32];
#pragma unroll
    for (int k = 0; k < 32; k += 4)
        *(float4*)&wdt[k] = *(const float4*)(Wdt_l + (size_t)d * 32 + k);
    const float bdt_d = bdt_l[d];

    const size_t base64 = ((size_t)b * T_ + (size_t)ch * CL_) * 64;
    float* sflat = &sAll[0][0];
    for (int i = tid; i < CL_ * 64; i += 256) sflat[i] = dbc[base64 + i];
    __syncthreads();

    float sdl = 0.f;
    if (geo) {
        for (int tt = 0; tt < CL_; ++tt) {
            float t = bdt_d;
#pragma unroll
            for (int k = 0; k < 32; k += 4) {
                const float4 dv = *(const float4*)&sAll[tt][k];
                t = fmaf(dv.x, wdt[k + 0], t);
                t = fmaf(dv.y, wdt[k + 1], t);
                t = fmaf(dv.z, wdt[k + 2], t);
                t = fmaf(dv.w, wdt[k + 3], t);
            }
            const float dl = softplus_f(t);
            sdl += dl;
            const size_t m = (size_t)b * T_ + ch * CL_ + tt;
            const float du = dl * u[m * DI_ + d];
            const float r = exp2f(dl * a2[0]);
            float dA = r;
#pragma unroll
            for (int n = 0; n < N_; ++n) {
                hs[n] = fmaf(dA, hs[n], du * sAll[tt][32 + n]);
                dA *= r;
            }
        }
    } else {
        for (int tt = 0; tt < CL_; ++tt) {
            float t = bdt_d;
#pragma unroll
            for (int k = 0; k < 32; k += 4) {
                const float4 dv = *(const float4*)&sAll[tt][k];
                t = fmaf(dv.x, wdt[k + 0], t);
                t = fmaf(dv.y, wdt[k + 1], t);
                t = fmaf(dv.z, wdt[k + 2], t);
                t = fmaf(dv.w, wdt[k + 3], t);
            }
            const float dl = softplus_f(t);
            sdl += dl;
            const size_t m = (size_t)b * T_ + ch * CL_ + tt;
            const float du = dl * u[m * DI_ + d];
#pragma unroll
            for (int n = 0; n < N_; ++n) {
                const float dA = exp2f(dl * a2[n]);
                hs[n] = fmaf(dA, hs[n], du * sAll[tt][32 + n]);
            }
        }
    }
#pragma unroll
    for (int n = 0; n < N_; ++n) {
        const size_t idx = (size_t)(((b * NCH_ + ch) * N_ + n) << 10) + d;
        P[idx] = exp2f(sdl * a2[n]);   // == product of per-step exp2(dl*a2[n])
        S[idx] = hs[n];
    }
}

__global__ __launch_bounds__(256) void scan_carry(
    const float* __restrict__ P, float* __restrict__ S)
{
    const size_t gid = (size_t)blockIdx.x * 256 + threadIdx.x;
    const int d = (int)(gid & 1023);
    const int n = (int)((gid >> 10) & 15);
    const int b = (int)(gid >> 14);
    float hc = 0.f;
    for (int ch = 0; ch < NCH_; ++ch) {
        const size_t idx = (size_t)(((b * NCH_ + ch) * N_ + n) << 10) + d;
        const float p = P[idx], s = S[idx];
        S[idx] = hc;
        hc = fmaf(p, hc, s);
    }
}

__global__ __launch_bounds__(256) void scan_pass3(
    float* __restrict__ xz, const float* __restrict__ u,
    const float* __restrict__ dbc, const float* __restrict__ A_log_l,
    const float* __restrict__ Wdt_l, const float* __restrict__ bdt_l,
    const float* __restrict__ Dp_l, const float* __restrict__ S,
    unsigned int* __restrict__ gmax)
{
    __shared__ __align__(16) float sAll[CL_][64];
    const int tid = threadIdx.x;
    const int b = blockIdx.x, ch = blockIdx.z;
    const int d = (blockIdx.y << 8) + tid;

    float a2[N_], hs[N_];
#pragma unroll
    for (int n = 0; n < N_; ++n) {
        a2[n] = -__expf(A_log_l[d * N_ + n]) * 1.44269504f;
        hs[n] = S[(size_t)(((b * NCH_ + ch) * N_ + n) << 10) + d];
    }
    const bool geo = geo_check(a2);
    float wdt[32];
#pragma unroll
    for (int k = 0; k < 32; k += 4)
        *(float4*)&wdt[k] = *(const float4*)(Wdt_l + (size_t)d * 32 + k);
    const float bdt_d = bdt_l[d];
    const float Dpd = Dp_l[d];

    const size_t base64 = ((size_t)b * T_ + (size_t)ch * CL_) * 64;
    float* sflat = &sAll[0][0];
    for (int i = tid; i < CL_ * 64; i += 256) sflat[i] = dbc[base64 + i];
    __syncthreads();

    float gm = 0.f;
    if (geo) {
        for (int tt = 0; tt < CL_; ++tt) {
            float t = bdt_d;
#pragma unroll
            for (int k = 0; k < 32; k += 4) {
                const float4 dv = *(const float4*)&sAll[tt][k];
                t = fmaf(dv.x, wdt[k + 0], t);
                t = fmaf(dv.y, wdt[k + 1], t);
                t = fmaf(dv.z, wdt[k + 2], t);
                t = fmaf(dv.w, wdt[k + 3], t);
            }
            const float dl = softplus_f(t);
            const size_t m = (size_t)b * T_ + ch * CL_ + tt;
            const float uv = u[m * DI_ + d];
            const float du = dl * uv;
            const float r = exp2f(dl * a2[0]);
            float dA = r;
            float yv = 0.f;
#pragma unroll
            for (int n = 0; n < N_; ++n) {
                hs[n] = fmaf(dA, hs[n], du * sAll[tt][32 + n]);
                yv = fmaf(hs[n], sAll[tt][48 + n], yv);
                dA *= r;
            }
            yv = fmaf(uv, Dpd, yv);
            const float g = yv * silu_f(xz[m * 2048 + DI_ + d]);
            xz[m * 2048 + d] = g;
            gm = fmaxf(gm, fabsf(g));
        }
    } else {
        for (int tt = 0; tt < CL_; ++tt) {
            float t = bdt_d;
#pragma unroll
            for (int k = 0; k < 32; k += 4) {
                const float4 dv = *(const float4*)&sAll[tt][k];
                t = fmaf(dv.x, wdt[k + 0], t);
                t = fmaf(dv.y, wdt[k + 1], t);
                t = fmaf(dv.z, wdt[k + 2], t);
                t = fmaf(dv.w, wdt[k + 3], t);
            }
            const float dl = softplus_f(t);
            const size_t m = (size_t)b * T_ + ch * CL_ + tt;
            const float uv = u[m * DI_ + d];
            const float du = dl * uv;
            float yv = 0.f;
#pragma unroll
            for (int n = 0; n < N_; ++n) {
                const float dA = exp2f(dl * a2[n]);
                hs[n] = fmaf(dA, hs[n], du * sAll[tt][32 + n]);
                yv = fmaf(hs[n], sAll[tt][48 + n], yv);
            }
            yv = fmaf(uv, Dpd, yv);
            const float g = yv * silu_f(xz[m * 2048 + DI_ + d]);
            xz[m * 2048 + d] = g;
            gm = fmaxf(gm, fabsf(g));
        }
    }
#pragma unroll
    for (int off = 32; off; off >>= 1) gm = fmaxf(gm, __shfl_down(gm, off));
    if ((tid & 63) == 0) atomicMax(gmax, __float_as_uint(gm));
}

extern "C" void kernel_launch(void* const* d_in, const int* in_sizes, int n_in,
                              void* d_out, int out_size, void* d_ws, size_t ws_size,
                              hipStream_t stream) {
    const float* x     = (const float*)d_in[0];
    const float* Wi    = (const float*)d_in[1];
    const float* bi    = (const float*)d_in[2];
    const float* Win   = (const float*)d_in[3];
    const float* convw = (const float*)d_in[4];
    const float* convb = (const float*)d_in[5];
    const float* Wx    = (const float*)d_in[6];
    const float* Wdt   = (const float*)d_in[7];
    const float* bdt   = (const float*)d_in[8];
    const float* A_log = (const float*)d_in[9];
    const float* Dp    = (const float*)d_in[10];
    const float* Wout  = (const float*)d_in[11];
    const float* Wo    = (const float*)d_in[12];
    const float* bo    = (const float*)d_in[13];
    float* out = (float*)d_out;

    // Per-row f32: xz 2048 + u 1024 + dbc 64 + hPS 512 (h | scan P,S) = 3648.
    const size_t rowf = 3648;
    const size_t wextra =
        (3 * 1048576 + 3 * 524288 + 65536 + 3 * 65536) / 2 + 32;
    int CB = BB_;
    while (CB > 1 && ((size_t)CB * T_ * rowf + wextra) * sizeof(float) > ws_size) CB >>= 1;
    const size_t Mc = (size_t)CB * T_;

    const dim3 blk(256);
    const int rowTiles = (int)(Mc / 128);

    float* ws   = (float*)d_ws;
    float* xz   = ws;                    // Mc*2048 (xin dead after conv; g | z)
    float* u    = xz + Mc * 2048;        // Mc*1024
    float* dbc  = u  + Mc * 1024;        // Mc*64
    float* hPS  = dbc + Mc * 64;         // Mc*512: h (ld 512) / scan P,S
    float* hb   = hPS;
    float* Pbuf = hPS;                               // CB*NCH*N*DI floats
    float* Sbuf = hPS + (size_t)CB * NCH_ * N_ * DI_;
    unsigned short* WinH  = (unsigned short*)(hPS + Mc * 512);
    unsigned short* WoutH = WinH + 3 * 1048576;
    unsigned short* WoH   = WoutH + 3 * 524288;
    unsigned short* WxH   = WoH + 65536;
    unsigned int* scales  = (unsigned int*)(WxH + 3 * 65536);
    // slots: 0-2 Win, 3-5 Wout, 6 Wo, 7-9 Wx,
    //        10..13 h[0..3], 14-16 g[l], 17-19 u[l]

    hipMemsetAsync(scales, 0, 32 * sizeof(unsigned int), stream);

    amax_all<<<dim3(128, 1, 10), blk, 0, stream>>>(Win, Wout, Wx, Wo, scales);
    cast_all<<<dim3(64, 1, 10), blk, 0, stream>>>(
        Win, Wout, Wx, Wo, WinH, WoutH, WxH, WoH, scales);

    for (int c = 0; c < BB_ / CB; ++c) {
        const float* x_c = x + (size_t)c * Mc * DIN_;
        float* out_c     = out + (size_t)c * Mc * DOUT_;

        hipMemsetAsync(scales + 10, 0, 10 * sizeof(unsigned int), stream);

        // h = x @ Wi.T + bi  (fp32, K=64) -> hb (ld 512), amax -> h[0]
        gemm_in<<<dim3(D_ / 128, rowTiles), blk, 0, stream>>>(
            x_c, DIN_, Wi, DIN_, bi, hb, D_, DIN_, scales + 10);

        for (int l = 0; l < L_; ++l) {
            const float* cw_l   = convw + (size_t)l * DI_ * DC_;
            const float* cb_l   = convb + (size_t)l * DI_;
            const float* Wdt_l  = Wdt  + (size_t)l * DI_ * R_;
            const float* bdt_l  = bdt  + (size_t)l * DI_;
            const float* Alog_l = A_log + (size_t)l * DI_ * N_;
            const float* Dp_l   = Dp   + (size_t)l * DI_;

            // xz = h @ Win.T  (A fp32 staged-cast, B async-lds, pipelined)
            gemm_f32a_t128<0><<<dim3(2048 / 128, rowTiles), blk, 0, stream>>>(
                hb, D_, WinH + (size_t)l * 1048576, D_, nullptr,
                xz, 2048, D_, scales + 10 + l, scales + l, nullptr);

            // u = silu(causal_dwconv(xin) + cb), fused u amax
            conv_silu_kernel<<<dim3(2048), blk, 0, stream>>>(
                xz, cw_l, cb_l, u, Mc * DI_ / 4, scales + 17 + l);

            // dbc = u @ Wx.T  (f16 MFMA 128x64)
            gemm_f16u_t64n<<<dim3(1, rowTiles), blk, 0, stream>>>(
                u, DI_, WxH + (size_t)l * 65536, DI_, dbc, 64, DI_,
                scales + 17 + l, scales + 7 + l);

            // chunk-parallel scan with fused delta; g -> xz[:, :1024]
            scan_pass1<<<dim3(CB, DI_ / 256, NCH_), blk, 0, stream>>>(
                u, dbc, Alog_l, Wdt_l, bdt_l, Pbuf, Sbuf);
            scan_carry<<<dim3(CB * 64), blk, 0, stream>>>(Pbuf, Sbuf);
            scan_pass3<<<dim3(CB, DI_ / 256, NCH_), blk, 0, stream>>>(
                xz, u, dbc, Alog_l, Wdt_l, bdt_l, Dp_l, Sbuf, scales + 14 + l);

            // h = g @ Wout.T  (A fp32 staged-cast) -> hb (P/S dead)
            gemm_f32a_t128<0><<<dim3(D_ / 128, rowTiles), blk, 0, stream>>>(
                xz, 2048, WoutH + (size_t)l * 524288, DI_, nullptr,
                hb, D_, DI_, scales + 14 + l, scales + 3 + l, scales + 11 + l);
        }

        // out = tanh(h @ Wo.T + bo)
        gemm_f32a_t128<3><<<dim3(DOUT_ / 128, rowTiles), blk, 0, stream>>>(
            hb, D_, WoH, D_, bo, out_c, DOUT_, D_,
            scales + 13, scales + 6, nullptr);
    }
}